// Round 6
// baseline (2185.435 us; speedup 1.0000x reference)
//
#include <hip/hip_runtime.h>

#define S_LEN 512
#define HID   512
#define FEAT  26
#define NCLS  20
#define DRING 16

typedef short bf16x8 __attribute__((ext_vector_type(8)));
typedef float f32x4  __attribute__((ext_vector_type(4)));

__device__ __forceinline__ unsigned short f2bf(float f) {   // RNE
    unsigned u = __builtin_bit_cast(unsigned, f);
    unsigned r = (u + 0x7FFFu + ((u >> 16) & 1u)) >> 16;
    return (unsigned short)r;
}
__device__ __forceinline__ float sigm(float x) { return 1.f / (1.f + __expf(-x)); }
__device__ __forceinline__ float tanh_f(float x) {
    float xc = fminf(fmaxf(x, -15.f), 15.f);
    float t = __expf(-2.f * xc);
    return (1.f - t) / (1.f + t);
}

// ---------------- system-scope (sc0 sc1, MALL) helpers ----------------
__device__ __forceinline__ void load4_coherent(const unsigned short* p,
                                               uint4& a0, uint4& a1, uint4& a2, uint4& a3) {
    asm volatile(
        "global_load_dwordx4 %0, %4, off sc0 sc1\n\t"
        "global_load_dwordx4 %1, %5, off sc0 sc1\n\t"
        "global_load_dwordx4 %2, %6, off sc0 sc1\n\t"
        "global_load_dwordx4 %3, %7, off sc0 sc1\n\t"
        "s_waitcnt vmcnt(0)"
        : "=&v"(a0), "=&v"(a1), "=&v"(a2), "=&v"(a3)
        : "v"(p), "v"(p + 8), "v"(p + 16), "v"(p + 24)
        : "memory");
}
__device__ __forceinline__ void store_coherent(unsigned short* p, unsigned d) {
    asm volatile(
        "global_store_dword %0, %1, off sc0 sc1\n\t"
        "s_waitcnt vmcnt(0)"
        :: "v"(p), "v"(d) : "memory");
}
__device__ __forceinline__ void store_coherent_x2(unsigned short* p, unsigned long long d) {
    asm volatile(
        "global_store_dwordx2 %0, %1, off sc0 sc1\n\t"
        "s_waitcnt vmcnt(0)"
        :: "v"(p), "v"(d) : "memory");
}
__device__ __forceinline__ void store_u32_nowait(unsigned* p, unsigned d) {
    asm volatile("global_store_dword %0, %1, off sc0 sc1" :: "v"(p), "v"(d) : "memory");
}
__device__ __forceinline__ unsigned load_u32_coherent(const unsigned* p) {
    unsigned v;
    asm volatile("global_load_dword %0, %1, off sc0 sc1\n\ts_waitcnt vmcnt(0)"
                 : "=v"(v) : "v"(p) : "memory");
    return v;
}
__device__ __forceinline__ void store_u32_sys_wait(unsigned* p, unsigned d) {
    asm volatile("global_store_dword %0, %1, off sc0 sc1\n\ts_waitcnt vmcnt(0)"
                 :: "v"(p), "v"(d) : "memory");
}
// 2x contiguous 16B system-scope loads, NO wait (caller manages vmcnt).
__device__ __forceinline__ void load2_nw_sys(const unsigned short* p, uint4& a0, uint4& a1) {
    asm volatile(
        "global_load_dwordx4 %0, %2, off sc0 sc1\n\t"
        "global_load_dwordx4 %1, %3, off sc0 sc1"
        : "=&v"(a0), "=&v"(a1) : "v"(p), "v"(p + 8) : "memory");
}
// 16B flag-quad load (4 per-wave flags of one producer), waits.
__device__ __forceinline__ uint4 load_flags4_sys(const unsigned* p) {
    uint4 v;
    asm volatile("global_load_dwordx4 %0, %1, off sc0 sc1\n\ts_waitcnt vmcnt(0)"
                 : "=v"(v) : "v"(p) : "memory");
    return v;
}

// ---------------- XCD-local (sc0 only, per-XCD L2) helpers ----------------
__device__ __forceinline__ void load4_l2(const unsigned short* p,
                                         uint4& a0, uint4& a1, uint4& a2, uint4& a3) {
    asm volatile(
        "global_load_dwordx4 %0, %4, off sc0\n\t"
        "global_load_dwordx4 %1, %5, off sc0\n\t"
        "global_load_dwordx4 %2, %6, off sc0\n\t"
        "global_load_dwordx4 %3, %7, off sc0\n\t"
        "s_waitcnt vmcnt(0)"
        : "=&v"(a0), "=&v"(a1), "=&v"(a2), "=&v"(a3)
        : "v"(p), "v"(p + 8), "v"(p + 16), "v"(p + 24)
        : "memory");
}
__device__ __forceinline__ void store_l2_x2(unsigned short* p, unsigned long long d) {
    asm volatile(
        "global_store_dwordx2 %0, %1, off sc0\n\t"
        "s_waitcnt vmcnt(0)"
        :: "v"(p), "v"(d) : "memory");
}
__device__ __forceinline__ void store_u32_nowait_l2(unsigned* p, unsigned d) {
    asm volatile("global_store_dword %0, %1, off sc0" :: "v"(p), "v"(d) : "memory");
}
__device__ __forceinline__ unsigned load_u32_l2(const unsigned* p) {
    unsigned v;
    asm volatile("global_load_dword %0, %1, off sc0\n\ts_waitcnt vmcnt(0)"
                 : "=v"(v) : "v"(p) : "memory");
    return v;
}
// 2x contiguous 16B L2-scope loads, NO wait (caller manages vmcnt).
__device__ __forceinline__ void load2_nw_l2(const unsigned short* p, uint4& a0, uint4& a1) {
    asm volatile(
        "global_load_dwordx4 %0, %2, off sc0\n\t"
        "global_load_dwordx4 %1, %3, off sc0"
        : "=&v"(a0), "=&v"(a1) : "v"(p), "v"(p + 8) : "memory");
}
// 16B flag-quad load (4 per-wave flags of one producer), waits.
__device__ __forceinline__ uint4 load_flags4_l2(const unsigned* p) {
    uint4 v;
    asm volatile("global_load_dwordx4 %0, %1, off sc0\n\ts_waitcnt vmcnt(0)"
                 : "=v"(v) : "v"(p) : "memory");
    return v;
}
__device__ __forceinline__ unsigned min4u(uint4 f) {
    unsigned a = f.x < f.y ? f.x : f.y;
    unsigned b = f.z < f.w ? f.z : f.w;
    return a < b ? a : b;
}

// zero sync words, convert w1/w2 fp32 -> bf16
__global__ void prep_kernel(const float* __restrict__ w1, const float* __restrict__ w2,
                            unsigned short* __restrict__ w1b, unsigned short* __restrict__ w2b,
                            unsigned* __restrict__ syncw, int nclear) {
    int i = blockIdx.x * 256 + threadIdx.x;
    if (i < nclear) syncw[i] = 0u;
    if (i < 256 * 512) w1b[i] = f2bf(w1[i]);
    if (i < NCLS * 256) w2b[i] = f2bf(w2[i]);
}

// ============================================================================
// BIG-WS PATH: 256 wgs on 256 CUs (1 wg/CU).
// Round-6 = Round-4 structure (best verified: split-staging pipeline, x staged
// cooperatively at loop top, g1 loads in flight across barrier #1) + ONE change:
//  - per-wave flags (dw0..3 of each producer slot): each wave publishes right
//    after its OWN h-store ack (no closing-barrier wait). Consumers poll with
//    lanes 0..7 issuing ONE dwordx4 per producer (16B contiguous quad) and a
//    3-op min reduce -- identical request count to the R4 poll.
//  - closing barrier is lgkm-only s_barrier (per-wave acks already done).
// ============================================================================
__global__ __launch_bounds__(256, 1) void lstm_big_kernel(
    const float* __restrict__ x,
    const float* __restrict__ w_ih,
    const float* __restrict__ w_hh,
    const float* __restrict__ b_ih,
    const float* __restrict__ b_hh,
    const unsigned short* __restrict__ w1b,
    const float* __restrict__ b1,
    const unsigned short* __restrict__ w2b,
    const float* __restrict__ b2,
    float* __restrict__ out,
    unsigned short* __restrict__ hs,   // [16][S][16][HID] bf16
    unsigned* __restrict__ flags)      // [16][8] x 16-dword; dw0..3=wave flags, dw8/9=xcc
{
    const int tid  = threadIdx.x;
    const int wave = tid >> 6;
    const int lane = tid & 63;
    const int quad = lane >> 4;
    const int l16  = lane & 15;

    // ---- XCD-affinity role remap ----
    const int  bx      = blockIdx.x;
    const int  xasm    = bx & 7;          // assumed XCD under round-robin
    const int  kslt    = bx >> 3;         // slot within assumed XCD (0..31)
    const bool is_lstm = (kslt < 16);
    const int  ksub    = is_lstm ? kslt : (kslt - 16);
    const int  clust   = xasm * 2 + (ksub >> 3);
    const int  sub     = ksub & 7;        // wic (LSTM) or m (MLP)

    __shared__ __align__(16) unsigned short At[16 * 552];
    __shared__ __align__(16) unsigned short hid[16 * 264];  // MLP only
    __shared__ float lg[16 * 24];                            // MLP only
    __shared__ unsigned rdy;
    __shared__ unsigned fastf;
    if (tid == 0) rdy = 0u;

    // ---- runtime same-XCD verification (one-time) ----
    {
        unsigned xcc;
        asm volatile("s_getreg_b32 %0, hwreg(HW_REG_XCC_ID)" : "=s"(xcc));
        if (tid == 0) {
            unsigned* slot = flags + (clust * 8 + sub) * 16 + (is_lstm ? 8 : 9);
            store_u32_sys_wait(slot, (xcc & 0xFu) + 1u);
        }
        if (wave == 0) {
            const unsigned* ps = flags + (clust * 8 + (lane & 7)) * 16 + ((lane & 8) ? 9 : 8);
            unsigned myx = 1u;
            for (;;) {
                unsigned v = 1u;
                if (lane < 16) v = load_u32_coherent(ps);
                if (__ballot(v != 0u) == ~0ull) { myx = v; break; }
                __builtin_amdgcn_s_sleep(2);
            }
            unsigned ref = __shfl(myx, 0);
            bool eq = (lane >= 16) || (myx == ref);
            if (tid == 0) fastf = (__ballot(eq) == ~0ull) ? 1u : 0u;
        }
    }
    __syncthreads();
    const bool fast = (fastf != 0u);

    if (is_lstm) {
        // =============== LSTM role ===============
        const int wic = sub;
        const int B0  = clust * 16;
        const int U0  = wic * 64;

        // Weights as the MFMA *A* operand: lane holds row (unit = U0+wave*16+l16)
        // for all 4 gates, k-slice = kk*32 + quad*8.
        bf16x8 bB[4][17];           // kk 0..15 = w_hh, kk 16 = w_ih
#pragma unroll
        for (int g = 0; g < 4; ++g) {
            const int row = g * 512 + U0 + wave * 16 + l16;
            const float* wrow = w_hh + (size_t)row * HID;
#pragma unroll
            for (int kk = 0; kk < 16; ++kk) {
                const float* p = wrow + kk * 32 + quad * 8;
                bf16x8 v;
#pragma unroll
                for (int j = 0; j < 8; ++j) v[j] = (short)f2bf(p[j]);
                bB[g][kk] = v;
            }
            const float* irow = w_ih + (size_t)row * FEAT;
            bf16x8 v;
#pragma unroll
            for (int j = 0; j < 8; ++j) {
                int ftr = quad * 8 + j;
                v[j] = (ftr < FEAT) ? (short)f2bf(irow[ftr]) : (short)0;
            }
            bB[g][16] = v;
        }

        // D[m=quad*4+r][n=batch l16]; bias folded into MFMA C-init.
        f32x4 biasv[4];
#pragma unroll
        for (int g = 0; g < 4; ++g)
#pragma unroll
            for (int r = 0; r < 4; ++r) {
                int rr = g * 512 + U0 + wave * 16 + quad * 4 + r;
                biasv[g][r] = b_ih[rr] + b_hh[rr];
            }
        float cst[4] = {0.f, 0.f, 0.f, 0.f};   // c-state: batch l16, units quad*4+r

        const int sm = tid >> 4;
        const int sc = tid & 15;
        unsigned short* hsc = hs + (size_t)clust * S_LEN * 16 * HID;
        unsigned* myflag = flags + (clust * 8 + wic) * 16;
        // lanes 0..7 each own one producer's 16B flag quad
        const unsigned* peerq = flags + (clust * 8 + (lane & 7)) * 16;

        for (int t = 0; t < S_LEN; ++t) {
            {   // stage x_t (cooperative, single copy; overlaps poll)
                unsigned pk = 0u;
                if (sc <= 12) {
                    float2 xv = *(const float2*)(x + ((size_t)(B0 + sm) * S_LEN + t) * FEAT + sc * 2);
                    pk = (unsigned)f2bf(xv.x) | ((unsigned)f2bf(xv.y) << 16);
                }
                *(unsigned*)(At + sm * 552 + 512 + sc * 2) = pk;
            }

            f32x4 acc[4];
#pragma unroll
            for (int g = 0; g < 4; ++g) acc[g] = biasv[g];

            if (t > 0) {
                const unsigned tt = (unsigned)t;
                // poll: lanes 0..7, one dwordx4 per producer, min over 4 wave flags.
                // Gate on g0 (producers 0-3); capture g1 in the same ballot.
                unsigned long long bal;
                for (;;) {
                    unsigned v = ~0u;
                    if (lane < 8) {
                        uint4 f4 = fast ? load_flags4_l2(peerq) : load_flags4_sys(peerq);
                        v = min4u(f4);
                    }
                    bal = __ballot(v >= tt);
                    if ((bal & 0xFull) == 0xFull) break;
                    if (!fast) __builtin_amdgcn_s_sleep(1);
                }
                const bool g1ok = ((bal >> 4) & 0xFull) == 0xFull;

                // issue g0 staging loads (h cols 0..255), 32B/thread, no wait
                const unsigned short* srow = hsc + ((size_t)(t - 1) * 16 + sm) * HID;
                uint4 s0, s1, s2, s3;
                if (fast) load2_nw_l2(srow + sc * 16, s0, s1);
                else      load2_nw_sys(srow + sc * 16, s0, s1);

                if (!g1ok) {   // rare: finish waiting for producers 4-7
                    for (;;) {
                        unsigned v = ~0u;
                        if (lane >= 4 && lane < 8) {
                            uint4 f4 = fast ? load_flags4_l2(peerq) : load_flags4_sys(peerq);
                            v = min4u(f4);
                        }
                        unsigned long long b2_ = __ballot(v >= tt);
                        if (((b2_ >> 4) & 0xFull) == 0xFull) break;
                        if (!fast) __builtin_amdgcn_s_sleep(1);
                    }
                }
                asm volatile("s_waitcnt vmcnt(0)" ::: "memory");
                __builtin_amdgcn_sched_barrier(0);
                {   // LDS write g0
                    unsigned short* dst = At + sm * 552 + sc * 16;
                    *(uint4*)(dst)     = s0;
                    *(uint4*)(dst + 8) = s1;
                }
                // issue g1 staging loads (h cols 256..511) -- stay in flight
                // across the barrier, land during MFMA phase A
                if (fast) load2_nw_l2(srow + 256 + sc * 16, s2, s3);
                else      load2_nw_sys(srow + 256 + sc * 16, s2, s3);

                // barrier #1: LDS (g0 + x) visible; vmcnt NOT drained
                asm volatile("s_waitcnt lgkmcnt(0)" ::: "memory");
                __builtin_amdgcn_sched_barrier(0);
                __builtin_amdgcn_s_barrier();

                // MFMA phase A: x (kk16) + k-slices 0..7
                const unsigned short* arow = At + l16 * 552 + quad * 8;
                {
                    bf16x8 hx = __builtin_bit_cast(bf16x8, *(const uint4*)(arow + 16 * 32));
#pragma unroll
                    for (int g = 0; g < 4; ++g)
                        acc[g] = __builtin_amdgcn_mfma_f32_16x16x32_bf16(bB[g][16], hx, acc[g], 0, 0, 0);
                }
#pragma unroll
                for (int kk = 0; kk < 8; ++kk) {
                    bf16x8 h = __builtin_bit_cast(bf16x8, *(const uint4*)(arow + kk * 32));
#pragma unroll
                    for (int g = 0; g < 4; ++g)
                        acc[g] = __builtin_amdgcn_mfma_f32_16x16x32_bf16(bB[g][kk], h, acc[g], 0, 0, 0);
                }

                // g1 data arrived during phase A; write LDS, barrier #2
                asm volatile("s_waitcnt vmcnt(0)" ::: "memory");
                __builtin_amdgcn_sched_barrier(0);
                {
                    unsigned short* dst = At + sm * 552 + 256 + sc * 16;
                    *(uint4*)(dst)     = s2;
                    *(uint4*)(dst + 8) = s3;
                }
                asm volatile("s_waitcnt lgkmcnt(0)" ::: "memory");
                __builtin_amdgcn_sched_barrier(0);
                __builtin_amdgcn_s_barrier();

                // MFMA phase B: k-slices 8..15
#pragma unroll
                for (int kk = 8; kk < 16; ++kk) {
                    bf16x8 h = __builtin_bit_cast(bf16x8, *(const uint4*)(arow + kk * 32));
#pragma unroll
                    for (int g = 0; g < 4; ++g)
                        acc[g] = __builtin_amdgcn_mfma_f32_16x16x32_bf16(bB[g][kk], h, acc[g], 0, 0, 0);
                }
            } else {
                __syncthreads();   // x staged
                const unsigned short* arow = At + l16 * 552 + quad * 8;
                bf16x8 hx = __builtin_bit_cast(bf16x8, *(const uint4*)(arow + 16 * 32));
#pragma unroll
                for (int g = 0; g < 4; ++g)
                    acc[g] = __builtin_amdgcn_mfma_f32_16x16x32_bf16(bB[g][16], hx, acc[g], 0, 0, 0);
            }

            {   // gates fully in-register (bias already in acc)
                unsigned short hv[4];
#pragma unroll
                for (int r = 0; r < 4; ++r) {
                    float cn = sigm(acc[1][r]) * cst[r] + sigm(acc[0][r]) * tanh_f(acc[2][r]);
                    cst[r] = cn;
                    hv[r] = f2bf(sigm(acc[3][r]) * tanh_f(cn));
                }
                unsigned long long d = (unsigned long long)hv[0]
                                     | ((unsigned long long)hv[1] << 16)
                                     | ((unsigned long long)hv[2] << 32)
                                     | ((unsigned long long)hv[3] << 48);
                unsigned short* hp = hsc + ((size_t)t * 16 + l16) * HID
                                   + U0 + wave * 16 + quad * 4;
                if (fast) store_l2_x2(hp, d);    // acks THIS wave's store
                else      store_coherent_x2(hp, d);
            }
            // per-wave flag: publish right after OWN store ack (no barrier wait)
            if (lane == 0) {
                if (fast) store_u32_nowait_l2(myflag + wave, (unsigned)(t + 1));
                else      store_u32_nowait(myflag + wave, (unsigned)(t + 1));
            }
            // closing barrier (At reuse protect); lgkm-only
            asm volatile("s_waitcnt lgkmcnt(0)" ::: "memory");
            __builtin_amdgcn_s_barrier();
        }
    } else {
        // =============== MLP role (poll via per-producer flag quads) ===============
        const int mc  = clust;
        const int m   = sub;
        const int B0  = mc * 16;
        const unsigned* peerq = flags + (mc * 8 + (lane & 7)) * 16;
        const unsigned short* hsc = hs + (size_t)mc * S_LEN * 16 * HID;
        const int sm = tid >> 4;
        const int sc = tid & 15;

        for (int t = m; t < S_LEN; t += 8) {
            if (wave == 0) {
                for (;;) {
                    unsigned v = ~0u;
                    if (lane < 8) {
                        uint4 f4 = fast ? load_flags4_l2(peerq) : load_flags4_sys(peerq);
                        v = min4u(f4);
                    }
                    if (__ballot(v >= (unsigned)(t + 1)) == ~0ull) break;
                    __builtin_amdgcn_s_sleep(8);
                }
                if (lane == 0)
                    __hip_atomic_store(&rdy, (unsigned)(t + 1), __ATOMIC_RELAXED,
                                       __HIP_MEMORY_SCOPE_WORKGROUP);
            } else {
                while (__hip_atomic_load(&rdy, __ATOMIC_RELAXED,
                                         __HIP_MEMORY_SCOPE_WORKGROUP) < (unsigned)(t + 1))
                    __builtin_amdgcn_s_sleep(8);
            }
            {
                const unsigned short* src = hsc + ((size_t)t * 16 + sm) * HID + sc * 32;
                unsigned short* dst = At + sm * 552 + sc * 32;
                uint4 a0, a1, a2, a3;
                if (fast) load4_l2(src, a0, a1, a2, a3);
                else      load4_coherent(src, a0, a1, a2, a3);
                *(uint4*)(dst)      = a0;
                *(uint4*)(dst + 8)  = a1;
                *(uint4*)(dst + 16) = a2;
                *(uint4*)(dst + 24) = a3;
            }
            __syncthreads();

            f32x4 a1[4];
#pragma unroll
            for (int nt = 0; nt < 4; ++nt) a1[nt] = (f32x4){0.f, 0.f, 0.f, 0.f};
#pragma unroll
            for (int kk = 0; kk < 16; ++kk) {
                bf16x8 a = __builtin_bit_cast(
                    bf16x8, *(const uint4*)(At + l16 * 552 + kk * 32 + quad * 8));
#pragma unroll
                for (int nt = 0; nt < 4; ++nt) {
                    int n = wave * 64 + nt * 16 + l16;
                    bf16x8 b = __builtin_bit_cast(
                        bf16x8, *(const uint4*)(w1b + (size_t)n * 512 + kk * 32 + quad * 8));
                    a1[nt] = __builtin_amdgcn_mfma_f32_16x16x32_bf16(a, b, a1[nt], 0, 0, 0);
                }
            }
#pragma unroll
            for (int nt = 0; nt < 4; ++nt) {
                int n = wave * 64 + nt * 16 + l16;
                float bv = b1[n];
#pragma unroll
                for (int r = 0; r < 4; ++r)
                    hid[(quad * 4 + r) * 264 + n] = f2bf(fmaxf(a1[nt][r] + bv, 0.f));
            }
            __syncthreads();
            if (wave == 0) {
                f32x4 a2[2];
                a2[0] = (f32x4){0.f, 0.f, 0.f, 0.f};
                a2[1] = (f32x4){0.f, 0.f, 0.f, 0.f};
#pragma unroll
                for (int kk = 0; kk < 8; ++kk) {
                    bf16x8 a = __builtin_bit_cast(
                        bf16x8, *(const uint4*)(hid + l16 * 264 + kk * 32 + quad * 8));
#pragma unroll
                    for (int nt = 0; nt < 2; ++nt) {
                        int n = nt * 16 + l16;
                        bf16x8 b;
                        if (n < NCLS) {
                            b = __builtin_bit_cast(
                                bf16x8, *(const uint4*)(w2b + (size_t)n * 256 + kk * 32 + quad * 8));
                        } else {
                            uint4 z; z.x = z.y = z.z = z.w = 0u;
                            b = __builtin_bit_cast(bf16x8, z);
                        }
                        a2[nt] = __builtin_amdgcn_mfma_f32_16x16x32_bf16(a, b, a2[nt], 0, 0, 0);
                    }
                }
#pragma unroll
                for (int nt = 0; nt < 2; ++nt) {
                    int n = nt * 16 + l16;
                    if (n < NCLS) {
                        float bv = b2[n];
#pragma unroll
                        for (int r = 0; r < 4; ++r)
                            lg[(quad * 4 + r) * 24 + n] = a2[nt][r] + bv;
                    }
                }
            }
            __syncthreads();
            if (tid < 16) {
                float v[NCLS];
                float mx = -3.4e38f;
#pragma unroll
                for (int c = 0; c < NCLS; ++c) { v[c] = lg[tid * 24 + c]; mx = fmaxf(mx, v[c]); }
                float s = 0.f;
#pragma unroll
                for (int c = 0; c < NCLS; ++c) s += __expf(v[c] - mx);
                float lse = mx + __logf(s);
                float* orow = out + ((size_t)(B0 + tid) * S_LEN + t) * NCLS;
#pragma unroll
                for (int c = 0; c < NCLS; ++c) orow[c] = v[c] - lse;
            }
            __syncthreads();
        }
    }
}

// ============================================================================
// FALLBACK (small ws): unchanged. 384 wgs, 16x16 LSTM + 16x8 MLP,
// 16-slot ring + done backpressure.
// ============================================================================
__global__ __launch_bounds__(256, 2) void lstm_fused_kernel(
    const float* __restrict__ x, const float* __restrict__ w_ih,
    const float* __restrict__ w_hh, const float* __restrict__ b_ih,
    const float* __restrict__ b_hh, const unsigned short* __restrict__ w1b,
    const float* __restrict__ b1, const unsigned short* __restrict__ w2b,
    const float* __restrict__ b2, float* __restrict__ out,
    unsigned short* __restrict__ hb, unsigned* __restrict__ flags,
    unsigned* __restrict__ done)
{
    const int tid  = threadIdx.x;
    const int wave = tid >> 6;
    const int lane = tid & 63;
    const int quad = lane >> 4;
    const int l16  = lane & 15;
    const int wg   = blockIdx.x;

    __shared__ __align__(16) unsigned short At[16 * 552];
    __shared__ float zb[16 * 132];
    __shared__ __align__(16) unsigned short hid[16 * 264];
    __shared__ float lg[16 * 24];
    __shared__ unsigned rdy;
    if (tid == 0) rdy = 0u;
    __syncthreads();

    if (wg < 256) {
        const int clust = (wg & 7) * 2 + (wg >= 128 ? 1 : 0);
        const int wic   = (wg >> 3) & 15;
        const int B0    = clust * 16;
        const int U0    = wic * 32;

        bf16x8 bB[2][17];
#pragma unroll
        for (int tl = 0; tl < 2; ++tl) {
            const int row = wave * 512 + U0 + tl * 16 + l16;
            const float* wrow = w_hh + (size_t)row * HID;
#pragma unroll
            for (int kk = 0; kk < 16; ++kk) {
                const float* p = wrow + kk * 32 + quad * 8;
                bf16x8 v;
#pragma unroll
                for (int j = 0; j < 8; ++j) v[j] = (short)f2bf(p[j]);
                bB[tl][kk] = v;
            }
            const float* irow = w_ih + (size_t)row * FEAT;
            bf16x8 v;
#pragma unroll
            for (int j = 0; j < 8; ++j) {
                int ftr = quad * 8 + j;
                v[j] = (ftr < FEAT) ? (short)f2bf(irow[ftr]) : (short)0;
            }
            bB[tl][16] = v;
        }

        const int gb = tid >> 4;
        const int gu = tid & 15;
        float bias[2][4];
#pragma unroll
        for (int uu = 0; uu < 2; ++uu)
#pragma unroll
            for (int g = 0; g < 4; ++g) {
                int r = g * 512 + U0 + 2 * gu + uu;
                bias[uu][g] = b_ih[r] + b_hh[r];
            }
        float cst[2] = {0.f, 0.f};

        const int sm = tid >> 4;
        const int sc = tid & 15;
        unsigned short* hbc = hb + (size_t)clust * DRING * 16 * HID;
        unsigned* myflag = flags + (clust * 16 + wic) * 16;
        const unsigned* peer = flags + (clust * 16 + (lane & 15)) * 16;

        for (int t = 0; t < S_LEN; ++t) {
            {
                unsigned pk = 0u;
                if (sc <= 12) {
                    float2 xv = *(const float2*)(x + ((size_t)(B0 + sm) * S_LEN + t) * FEAT + sc * 2);
                    pk = (unsigned)f2bf(xv.x) | ((unsigned)f2bf(xv.y) << 16);
                }
                *(unsigned*)(At + sm * 552 + 512 + sc * 2) = pk;
            }
            if (t > 0) {
                if (wave == 0) {
                    if (t >= DRING && lane == 0) {
                        const unsigned* dn = done + (clust * 8 + (t & 7)) * 16;
                        while (load_u32_coherent(dn) < (unsigned)(t - (DRING - 1)))
                            __builtin_amdgcn_s_sleep(8);
                    }
                    for (;;) {
                        unsigned v = load_u32_coherent(peer);
                        if (__ballot(v >= (unsigned)t) == ~0ull) break;
                        __builtin_amdgcn_s_sleep(1);
                    }
                    if (lane == 0)
                        __hip_atomic_store(&rdy, (unsigned)t, __ATOMIC_RELAXED,
                                           __HIP_MEMORY_SCOPE_WORKGROUP);
                } else {
                    while (__hip_atomic_load(&rdy, __ATOMIC_RELAXED,
                                             __HIP_MEMORY_SCOPE_WORKGROUP) < (unsigned)t)
                        __builtin_amdgcn_s_sleep(1);
                }
                const unsigned short* src =
                    hbc + ((t - 1) & (DRING - 1)) * 16 * HID + sm * HID + sc * 32;
                unsigned short* dst = At + sm * 552 + sc * 32;
                uint4 a0, a1, a2, a3;
                load4_coherent(src, a0, a1, a2, a3);
                *(uint4*)(dst)      = a0;
                *(uint4*)(dst + 8)  = a1;
                *(uint4*)(dst + 16) = a2;
                *(uint4*)(dst + 24) = a3;
            }
            __syncthreads();

            f32x4 acc0 = {0.f, 0.f, 0.f, 0.f};
            f32x4 acc1 = {0.f, 0.f, 0.f, 0.f};
            const unsigned short* arow = At + l16 * 552 + quad * 8;
            if (t > 0) {
#pragma unroll
                for (int kk = 0; kk < 17; ++kk) {
                    bf16x8 a = __builtin_bit_cast(bf16x8, *(const uint4*)(arow + kk * 32));
                    acc0 = __builtin_amdgcn_mfma_f32_16x16x32_bf16(a, bB[0][kk], acc0, 0, 0, 0);
                    acc1 = __builtin_amdgcn_mfma_f32_16x16x32_bf16(a, bB[1][kk], acc1, 0, 0, 0);
                }
            } else {
                bf16x8 a = __builtin_bit_cast(bf16x8, *(const uint4*)(arow + 16 * 32));
                acc0 = __builtin_amdgcn_mfma_f32_16x16x32_bf16(a, bB[0][16], acc0, 0, 0, 0);
                acc1 = __builtin_amdgcn_mfma_f32_16x16x32_bf16(a, bB[1][16], acc1, 0, 0, 0);
            }
#pragma unroll
            for (int r = 0; r < 4; ++r) {
                zb[(quad * 4 + r) * 132 + wave * 32 + l16]      = acc0[r];
                zb[(quad * 4 + r) * 132 + wave * 32 + 16 + l16] = acc1[r];
            }
            __syncthreads();

            {
                const float* zrow = zb + gb * 132;
                unsigned short hv2[2];
#pragma unroll
                for (int uu = 0; uu < 2; ++uu) {
                    int u = 2 * gu + uu;
                    float zi = zrow[u]      + bias[uu][0];
                    float zf = zrow[32 + u] + bias[uu][1];
                    float zg = zrow[64 + u] + bias[uu][2];
                    float zo = zrow[96 + u] + bias[uu][3];
                    float cn = sigm(zf) * cst[uu] + sigm(zi) * tanh_f(zg);
                    cst[uu] = cn;
                    hv2[uu] = f2bf(sigm(zo) * tanh_f(cn));
                }
                unsigned short* hp =
                    hbc + (t & (DRING - 1)) * 16 * HID + gb * HID + U0 + 2 * gu;
                store_coherent(hp, (unsigned)hv2[0] | ((unsigned)hv2[1] << 16));
            }
            __syncthreads();
            if (tid == 0) store_u32_nowait(myflag, (unsigned)(t + 1));
        }
    } else {
        const int mwg  = wg - 256;
        const int mc   = mwg >> 3;
        const int m    = mwg & 7;
        const int B0   = mc * 16;
        unsigned* mydone = done + (mc * 8 + m) * 16;
        const unsigned* peer = flags + (mc * 16 + (lane & 15)) * 16;
        const unsigned short* hbc = hb + (size_t)mc * DRING * 16 * HID;
        const int sm = tid >> 4;
        const int sc = tid & 15;

        for (int t = m; t < S_LEN; t += 8) {
            if (wave == 0) {
                for (;;) {
                    unsigned v = load_u32_coherent(peer);
                    if (__ballot(v >= (unsigned)(t + 1)) == ~0ull) break;
                    __builtin_amdgcn_s_sleep(8);
                }
                if (lane == 0)
                    __hip_atomic_store(&rdy, (unsigned)(t + 1), __ATOMIC_RELAXED,
                                       __HIP_MEMORY_SCOPE_WORKGROUP);
            } else {
                while (__hip_atomic_load(&rdy, __ATOMIC_RELAXED,
                                         __HIP_MEMORY_SCOPE_WORKGROUP) < (unsigned)(t + 1))
                    __builtin_amdgcn_s_sleep(8);
            }
            {
                const unsigned short* src =
                    hbc + (t & (DRING - 1)) * 16 * HID + sm * HID + sc * 32;
                unsigned short* dst = At + sm * 552 + sc * 32;
                uint4 a0, a1, a2, a3;
                load4_coherent(src, a0, a1, a2, a3);
                *(uint4*)(dst)      = a0;
                *(uint4*)(dst + 8)  = a1;
                *(uint4*)(dst + 16) = a2;
                *(uint4*)(dst + 24) = a3;
            }
            __syncthreads();
            if (tid == 0) store_u32_nowait(mydone, (unsigned)(t + 1));

            f32x4 a1[4];
#pragma unroll
            for (int nt = 0; nt < 4; ++nt) a1[nt] = (f32x4){0.f, 0.f, 0.f, 0.f};
#pragma unroll
            for (int kk = 0; kk < 16; ++kk) {
                bf16x8 a = __builtin_bit_cast(
                    bf16x8, *(const uint4*)(At + l16 * 552 + kk * 32 + quad * 8));
#pragma unroll
                for (int nt = 0; nt < 4; ++nt) {
                    int n = wave * 64 + nt * 16 + l16;
                    bf16x8 b = __builtin_bit_cast(
                        bf16x8, *(const uint4*)(w1b + (size_t)n * 512 + kk * 32 + quad * 8));
                    a1[nt] = __builtin_amdgcn_mfma_f32_16x16x32_bf16(a, b, a1[nt], 0, 0, 0);
                }
            }
#pragma unroll
            for (int nt = 0; nt < 4; ++nt) {
                int n = wave * 64 + nt * 16 + l16;
                float bv = b1[n];
#pragma unroll
                for (int r = 0; r < 4; ++r)
                    hid[(quad * 4 + r) * 264 + n] = f2bf(fmaxf(a1[nt][r] + bv, 0.f));
            }
            __syncthreads();
            if (wave == 0) {
                f32x4 a2[2];
                a2[0] = (f32x4){0.f, 0.f, 0.f, 0.f};
                a2[1] = (f32x4){0.f, 0.f, 0.f, 0.f};
#pragma unroll
                for (int kk = 0; kk < 8; ++kk) {
                    bf16x8 a = __builtin_bit_cast(
                        bf16x8, *(const uint4*)(hid + l16 * 264 + kk * 32 + quad * 8));
#pragma unroll
                    for (int nt = 0; nt < 2; ++nt) {
                        int n = nt * 16 + l16;
                        bf16x8 b;
                        if (n < NCLS) {
                            b = __builtin_bit_cast(
                                bf16x8, *(const uint4*)(w2b + (size_t)n * 256 + kk * 32 + quad * 8));
                        } else {
                            uint4 z; z.x = z.y = z.z = z.w = 0u;
                            b = __builtin_bit_cast(bf16x8, z);
                        }
                        a2[nt] = __builtin_amdgcn_mfma_f32_16x16x32_bf16(a, b, a2[nt], 0, 0, 0);
                    }
                }
#pragma unroll
                for (int nt = 0; nt < 2; ++nt) {
                    int n = nt * 16 + l16;
                    if (n < NCLS) {
                        float bv = b2[n];
#pragma unroll
                        for (int r = 0; r < 4; ++r)
                            lg[(quad * 4 + r) * 24 + n] = a2[nt][r] + bv;
                    }
                }
            }
            __syncthreads();
            if (tid < 16) {
                float v[NCLS];
                float mx = -3.4e38f;
#pragma unroll
                for (int c = 0; c < NCLS; ++c) { v[c] = lg[tid * 24 + c]; mx = fmaxf(mx, v[c]); }
                float s = 0.f;
#pragma unroll
                for (int c = 0; c < NCLS; ++c) s += __expf(v[c] - mx);
                float lse = mx + __logf(s);
                float* orow = out + ((size_t)(B0 + tid) * S_LEN + t) * NCLS;
#pragma unroll
                for (int c = 0; c < NCLS; ++c) orow[c] = v[c] - lse;
            }
            __syncthreads();
        }
    }
}

extern "C" void kernel_launch(void* const* d_in, const int* in_sizes, int n_in,
                              void* d_out, int out_size, void* d_ws, size_t ws_size,
                              hipStream_t stream) {
    const float* x    = (const float*)d_in[0];
    const float* w_ih = (const float*)d_in[1];
    const float* w_hh = (const float*)d_in[2];
    const float* b_ih = (const float*)d_in[3];
    const float* b_hh = (const float*)d_in[4];
    const float* w1   = (const float*)d_in[5];
    const float* b1   = (const float*)d_in[6];
    const float* w2   = (const float*)d_in[7];
    const float* b2   = (const float*)d_in[8];
    char* ws = (char*)d_ws;

    const size_t HS_BYTES = (size_t)16 * S_LEN * 16 * HID * 2;   // 128 MB
    const size_t NEED_BIG = HS_BYTES + 8192 + 262144 + 10240;

    if (ws_size >= NEED_BIG) {
        unsigned short* hsb   = (unsigned short*)ws;
        unsigned*       flags = (unsigned*)(ws + HS_BYTES);
        unsigned short* w1b   = (unsigned short*)(ws + HS_BYTES + 8192);
        unsigned short* w2b   = (unsigned short*)(ws + HS_BYTES + 8192 + 262144);
        prep_kernel<<<512, 256, 0, stream>>>(w1, w2, w1b, w2b, flags, 2048);
        lstm_big_kernel<<<256, 256, 0, stream>>>(x, w_ih, w_hh, b_ih, b_hh,
                                                 w1b, b1, w2b, b2,
                                                 (float*)d_out, hsb, flags);
    } else {
        unsigned short* hb    = (unsigned short*)ws;
        unsigned*       flags = (unsigned*)(ws + 4194304);
        unsigned*       done  = (unsigned*)(ws + 4194304 + 16384);
        unsigned short* w1b   = (unsigned short*)(ws + 4194304 + 16384 + 8192);
        unsigned short* w2b   = (unsigned short*)(ws + 4194304 + 16384 + 8192 + 262144);
        prep_kernel<<<512, 256, 0, stream>>>(w1, w2, w1b, w2b, flags, 6144);
        lstm_fused_kernel<<<384, 256, 0, stream>>>(x, w_ih, w_hh, b_ih, b_hh,
                                                   w1b, b1, w2b, b2,
                                                   (float*)d_out, hb, flags, done);
    }
}

// Round 7
// 2065.982 us; speedup vs baseline: 1.0578x; 1.0578x over previous
//
#include <hip/hip_runtime.h>

#define S_LEN 512
#define HID   512
#define FEAT  26
#define NCLS  20
#define DRING 16

typedef short bf16x8 __attribute__((ext_vector_type(8)));
typedef float f32x4  __attribute__((ext_vector_type(4)));

__device__ __forceinline__ unsigned short f2bf(float f) {   // RNE
    unsigned u = __builtin_bit_cast(unsigned, f);
    unsigned r = (u + 0x7FFFu + ((u >> 16) & 1u)) >> 16;
    return (unsigned short)r;
}
__device__ __forceinline__ float sigm(float x) { return 1.f / (1.f + __expf(-x)); }
__device__ __forceinline__ float tanh_f(float x) {
    float xc = fminf(fmaxf(x, -15.f), 15.f);
    float t = __expf(-2.f * xc);
    return (1.f - t) / (1.f + t);
}

// ---------------- system-scope (sc0 sc1, MALL) helpers ----------------
__device__ __forceinline__ void load4_coherent(const unsigned short* p,
                                               uint4& a0, uint4& a1, uint4& a2, uint4& a3) {
    asm volatile(
        "global_load_dwordx4 %0, %4, off sc0 sc1\n\t"
        "global_load_dwordx4 %1, %5, off sc0 sc1\n\t"
        "global_load_dwordx4 %2, %6, off sc0 sc1\n\t"
        "global_load_dwordx4 %3, %7, off sc0 sc1\n\t"
        "s_waitcnt vmcnt(0)"
        : "=&v"(a0), "=&v"(a1), "=&v"(a2), "=&v"(a3)
        : "v"(p), "v"(p + 8), "v"(p + 16), "v"(p + 24)
        : "memory");
}
__device__ __forceinline__ void store_coherent(unsigned short* p, unsigned d) {
    asm volatile(
        "global_store_dword %0, %1, off sc0 sc1\n\t"
        "s_waitcnt vmcnt(0)"
        :: "v"(p), "v"(d) : "memory");
}
__device__ __forceinline__ void store_coherent_x2(unsigned short* p, unsigned long long d) {
    asm volatile(
        "global_store_dwordx2 %0, %1, off sc0 sc1\n\t"
        "s_waitcnt vmcnt(0)"
        :: "v"(p), "v"(d) : "memory");
}
__device__ __forceinline__ void store_u32_nowait(unsigned* p, unsigned d) {
    asm volatile("global_store_dword %0, %1, off sc0 sc1" :: "v"(p), "v"(d) : "memory");
}
__device__ __forceinline__ unsigned load_u32_coherent(const unsigned* p) {
    unsigned v;
    asm volatile("global_load_dword %0, %1, off sc0 sc1\n\ts_waitcnt vmcnt(0)"
                 : "=v"(v) : "v"(p) : "memory");
    return v;
}
__device__ __forceinline__ void store_u32_sys_wait(unsigned* p, unsigned d) {
    asm volatile("global_store_dword %0, %1, off sc0 sc1\n\ts_waitcnt vmcnt(0)"
                 :: "v"(p), "v"(d) : "memory");
}
// 2x contiguous 16B system-scope loads, NO wait (caller manages vmcnt).
__device__ __forceinline__ void load2_nw_sys(const unsigned short* p, uint4& a0, uint4& a1) {
    asm volatile(
        "global_load_dwordx4 %0, %2, off sc0 sc1\n\t"
        "global_load_dwordx4 %1, %3, off sc0 sc1"
        : "=&v"(a0), "=&v"(a1) : "v"(p), "v"(p + 8) : "memory");
}

// ---------------- XCD-local (sc0 only, per-XCD L2) helpers ----------------
__device__ __forceinline__ void load4_l2(const unsigned short* p,
                                         uint4& a0, uint4& a1, uint4& a2, uint4& a3) {
    asm volatile(
        "global_load_dwordx4 %0, %4, off sc0\n\t"
        "global_load_dwordx4 %1, %5, off sc0\n\t"
        "global_load_dwordx4 %2, %6, off sc0\n\t"
        "global_load_dwordx4 %3, %7, off sc0\n\t"
        "s_waitcnt vmcnt(0)"
        : "=&v"(a0), "=&v"(a1), "=&v"(a2), "=&v"(a3)
        : "v"(p), "v"(p + 8), "v"(p + 16), "v"(p + 24)
        : "memory");
}
__device__ __forceinline__ void store_l2_x2(unsigned short* p, unsigned long long d) {
    asm volatile(
        "global_store_dwordx2 %0, %1, off sc0\n\t"
        "s_waitcnt vmcnt(0)"
        :: "v"(p), "v"(d) : "memory");
}
__device__ __forceinline__ void store_u32_nowait_l2(unsigned* p, unsigned d) {
    asm volatile("global_store_dword %0, %1, off sc0" :: "v"(p), "v"(d) : "memory");
}
__device__ __forceinline__ unsigned load_u32_l2(const unsigned* p) {
    unsigned v;
    asm volatile("global_load_dword %0, %1, off sc0\n\ts_waitcnt vmcnt(0)"
                 : "=v"(v) : "v"(p) : "memory");
    return v;
}
// 2x contiguous 16B L2-scope loads, NO wait (caller manages vmcnt).
__device__ __forceinline__ void load2_nw_l2(const unsigned short* p, uint4& a0, uint4& a1) {
    asm volatile(
        "global_load_dwordx4 %0, %2, off sc0\n\t"
        "global_load_dwordx4 %1, %3, off sc0"
        : "=&v"(a0), "=&v"(a1) : "v"(p), "v"(p + 8) : "memory");
}

// zero sync words, convert w1/w2 fp32 -> bf16
__global__ void prep_kernel(const float* __restrict__ w1, const float* __restrict__ w2,
                            unsigned short* __restrict__ w1b, unsigned short* __restrict__ w2b,
                            unsigned* __restrict__ syncw, int nclear) {
    int i = blockIdx.x * 256 + threadIdx.x;
    if (i < nclear) syncw[i] = 0u;
    if (i < 256 * 512) w1b[i] = f2bf(w1[i]);
    if (i < NCLS * 256) w2b[i] = f2bf(w2[i]);
}

// ============================================================================
// BIG-WS PATH: 256 wgs on 256 CUs (1 wg/CU).
// Round-7 = Round-4 structure (best verified, 1945us: split-staging pipeline,
// single per-producer flag published by tid0 after closing __syncthreads)
// + ONE change: x_t load is issued NO-WAIT at loop top and staged to LDS
// AFTER the poll (the poll's own vmcnt(0) drains it for free, and the f2bf
// + ds_write overlap the g0 load round trip). Removes the ~150-250cy
// serialized x-load latency from the per-step chain. No new requests, no
// sync-protocol changes (R5/R6 lesson: those regress).
// ============================================================================
__global__ __launch_bounds__(256, 1) void lstm_big_kernel(
    const float* __restrict__ x,
    const float* __restrict__ w_ih,
    const float* __restrict__ w_hh,
    const float* __restrict__ b_ih,
    const float* __restrict__ b_hh,
    const unsigned short* __restrict__ w1b,
    const float* __restrict__ b1,
    const unsigned short* __restrict__ w2b,
    const float* __restrict__ b2,
    float* __restrict__ out,
    unsigned short* __restrict__ hs,   // [16][S][16][HID] bf16
    unsigned* __restrict__ flags)      // [16][8] x 16-dword stride; dw0=flag, dw8/dw9=xcc
{
    const int tid  = threadIdx.x;
    const int wave = tid >> 6;
    const int lane = tid & 63;
    const int quad = lane >> 4;
    const int l16  = lane & 15;

    // ---- XCD-affinity role remap ----
    const int  bx      = blockIdx.x;
    const int  xasm    = bx & 7;          // assumed XCD under round-robin
    const int  kslt    = bx >> 3;         // slot within assumed XCD (0..31)
    const bool is_lstm = (kslt < 16);
    const int  ksub    = is_lstm ? kslt : (kslt - 16);
    const int  clust   = xasm * 2 + (ksub >> 3);
    const int  sub     = ksub & 7;        // wic (LSTM) or m (MLP)

    __shared__ __align__(16) unsigned short At[16 * 552];
    __shared__ __align__(16) unsigned short hid[16 * 264];  // MLP only
    __shared__ float lg[16 * 24];                            // MLP only
    __shared__ unsigned rdy;
    __shared__ unsigned fastf;
    if (tid == 0) rdy = 0u;

    // ---- runtime same-XCD verification (one-time) ----
    {
        unsigned xcc;
        asm volatile("s_getreg_b32 %0, hwreg(HW_REG_XCC_ID)" : "=s"(xcc));
        if (tid == 0) {
            unsigned* slot = flags + (clust * 8 + sub) * 16 + (is_lstm ? 8 : 9);
            store_u32_sys_wait(slot, (xcc & 0xFu) + 1u);
        }
        if (wave == 0) {
            const unsigned* ps = flags + (clust * 8 + (lane & 7)) * 16 + ((lane & 8) ? 9 : 8);
            unsigned myx = 1u;
            for (;;) {
                unsigned v = 1u;
                if (lane < 16) v = load_u32_coherent(ps);
                if (__ballot(v != 0u) == ~0ull) { myx = v; break; }
                __builtin_amdgcn_s_sleep(2);
            }
            unsigned ref = __shfl(myx, 0);
            bool eq = (lane >= 16) || (myx == ref);
            if (tid == 0) fastf = (__ballot(eq) == ~0ull) ? 1u : 0u;
        }
    }
    __syncthreads();
    const bool fast = (fastf != 0u);

    if (is_lstm) {
        // =============== LSTM role ===============
        const int wic = sub;
        const int B0  = clust * 16;
        const int U0  = wic * 64;

        // Weights as the MFMA *A* operand: lane holds row (unit = U0+wave*16+l16)
        // for all 4 gates, k-slice = kk*32 + quad*8.
        bf16x8 bB[4][17];           // kk 0..15 = w_hh, kk 16 = w_ih
#pragma unroll
        for (int g = 0; g < 4; ++g) {
            const int row = g * 512 + U0 + wave * 16 + l16;
            const float* wrow = w_hh + (size_t)row * HID;
#pragma unroll
            for (int kk = 0; kk < 16; ++kk) {
                const float* p = wrow + kk * 32 + quad * 8;
                bf16x8 v;
#pragma unroll
                for (int j = 0; j < 8; ++j) v[j] = (short)f2bf(p[j]);
                bB[g][kk] = v;
            }
            const float* irow = w_ih + (size_t)row * FEAT;
            bf16x8 v;
#pragma unroll
            for (int j = 0; j < 8; ++j) {
                int ftr = quad * 8 + j;
                v[j] = (ftr < FEAT) ? (short)f2bf(irow[ftr]) : (short)0;
            }
            bB[g][16] = v;
        }

        // D[m=quad*4+r][n=batch l16]; bias folded into MFMA C-init.
        f32x4 biasv[4];
#pragma unroll
        for (int g = 0; g < 4; ++g)
#pragma unroll
            for (int r = 0; r < 4; ++r) {
                int rr = g * 512 + U0 + wave * 16 + quad * 4 + r;
                biasv[g][r] = b_ih[rr] + b_hh[rr];
            }
        float cst[4] = {0.f, 0.f, 0.f, 0.f};   // c-state: batch l16, units quad*4+r

        const int sm = tid >> 4;
        const int sc = tid & 15;
        unsigned short* hsc = hs + (size_t)clust * S_LEN * 16 * HID;
        unsigned* myflag = flags + (clust * 8 + wic) * 16;
        const unsigned* peer = flags + (clust * 8 + (lane & 7)) * 16;

        for (int t = 0; t < S_LEN; ++t) {
            f32x4 acc[4];
#pragma unroll
            for (int g = 0; g < 4; ++g) acc[g] = biasv[g];

            if (t > 0) {
                // ---- x_t: issue NO-WAIT load; drained for free by the poll's
                //      vmcnt(0); staged to LDS after the poll (under g0 flight)
                unsigned long long xq = 0ull;
                if (sc <= 12)
                    asm volatile("global_load_dwordx2 %0, %1, off"
                                 : "=v"(xq)
                                 : "v"(x + ((size_t)(B0 + sm) * S_LEN + t) * FEAT + sc * 2)
                                 : "memory");

                const unsigned tt = (unsigned)t;
                // poll all 8 flags; gate on g0 (producers 0-3), capture g1
                unsigned long long bal;
                for (;;) {
                    unsigned v = ~0u;
                    if (lane < 8) v = fast ? load_u32_l2(peer) : load_u32_coherent(peer);
                    bal = __ballot(v >= tt);
                    if ((bal & 0xFull) == 0xFull) break;
                    if (!fast) __builtin_amdgcn_s_sleep(1);
                }
                __builtin_amdgcn_sched_barrier(0);   // xq valid past this point
                const bool g1ok = ((bal >> 4) & 0xFull) == 0xFull;

                // issue g0 staging loads (h cols 0..255), 32B/thread, no wait
                const unsigned short* srow = hsc + ((size_t)(t - 1) * 16 + sm) * HID;
                uint4 s0, s1, s2, s3;
                if (fast) load2_nw_l2(srow + sc * 16, s0, s1);
                else      load2_nw_sys(srow + sc * 16, s0, s1);

                {   // x -> LDS (f2bf + ds_write overlap the g0 round trip)
                    float xlo = __builtin_bit_cast(float, (unsigned)xq);
                    float xhi = __builtin_bit_cast(float, (unsigned)(xq >> 32));
                    unsigned pk = (unsigned)f2bf(xlo) | ((unsigned)f2bf(xhi) << 16);
                    *(unsigned*)(At + sm * 552 + 512 + sc * 2) = pk;
                }

                if (!g1ok) {   // rare: finish waiting for producers 4-7
                    for (;;) {
                        unsigned v = ~0u;
                        if (lane >= 4 && lane < 8)
                            v = fast ? load_u32_l2(peer) : load_u32_coherent(peer);
                        unsigned long long b2_ = __ballot(v >= tt);
                        if (((b2_ >> 4) & 0xFull) == 0xFull) break;
                        if (!fast) __builtin_amdgcn_s_sleep(1);
                    }
                }
                asm volatile("s_waitcnt vmcnt(0)" ::: "memory");
                __builtin_amdgcn_sched_barrier(0);
                {   // LDS write g0
                    unsigned short* dst = At + sm * 552 + sc * 16;
                    *(uint4*)(dst)     = s0;
                    *(uint4*)(dst + 8) = s1;
                }
                // issue g1 staging loads (h cols 256..511) -- stay in flight
                // across the barrier, land during MFMA phase A
                if (fast) load2_nw_l2(srow + 256 + sc * 16, s2, s3);
                else      load2_nw_sys(srow + 256 + sc * 16, s2, s3);

                // barrier #1: LDS (g0 + x) visible; vmcnt NOT drained
                asm volatile("s_waitcnt lgkmcnt(0)" ::: "memory");
                __builtin_amdgcn_sched_barrier(0);
                __builtin_amdgcn_s_barrier();

                // MFMA phase A: x (kk16) + k-slices 0..7
                const unsigned short* arow = At + l16 * 552 + quad * 8;
                {
                    bf16x8 hx = __builtin_bit_cast(bf16x8, *(const uint4*)(arow + 16 * 32));
#pragma unroll
                    for (int g = 0; g < 4; ++g)
                        acc[g] = __builtin_amdgcn_mfma_f32_16x16x32_bf16(bB[g][16], hx, acc[g], 0, 0, 0);
                }
#pragma unroll
                for (int kk = 0; kk < 8; ++kk) {
                    bf16x8 h = __builtin_bit_cast(bf16x8, *(const uint4*)(arow + kk * 32));
#pragma unroll
                    for (int g = 0; g < 4; ++g)
                        acc[g] = __builtin_amdgcn_mfma_f32_16x16x32_bf16(bB[g][kk], h, acc[g], 0, 0, 0);
                }

                // g1 data arrived during phase A; write LDS, barrier #2
                asm volatile("s_waitcnt vmcnt(0)" ::: "memory");
                __builtin_amdgcn_sched_barrier(0);
                {
                    unsigned short* dst = At + sm * 552 + 256 + sc * 16;
                    *(uint4*)(dst)     = s2;
                    *(uint4*)(dst + 8) = s3;
                }
                asm volatile("s_waitcnt lgkmcnt(0)" ::: "memory");
                __builtin_amdgcn_sched_barrier(0);
                __builtin_amdgcn_s_barrier();

                // MFMA phase B: k-slices 8..15
#pragma unroll
                for (int kk = 8; kk < 16; ++kk) {
                    bf16x8 h = __builtin_bit_cast(bf16x8, *(const uint4*)(arow + kk * 32));
#pragma unroll
                    for (int g = 0; g < 4; ++g)
                        acc[g] = __builtin_amdgcn_mfma_f32_16x16x32_bf16(bB[g][kk], h, acc[g], 0, 0, 0);
                }
            } else {
                // t == 0: synchronous x staging (once)
                unsigned pk = 0u;
                if (sc <= 12) {
                    float2 xv = *(const float2*)(x + ((size_t)(B0 + sm) * S_LEN + t) * FEAT + sc * 2);
                    pk = (unsigned)f2bf(xv.x) | ((unsigned)f2bf(xv.y) << 16);
                }
                *(unsigned*)(At + sm * 552 + 512 + sc * 2) = pk;
                __syncthreads();
                const unsigned short* arow = At + l16 * 552 + quad * 8;
                bf16x8 hx = __builtin_bit_cast(bf16x8, *(const uint4*)(arow + 16 * 32));
#pragma unroll
                for (int g = 0; g < 4; ++g)
                    acc[g] = __builtin_amdgcn_mfma_f32_16x16x32_bf16(bB[g][16], hx, acc[g], 0, 0, 0);
            }

            {   // gates fully in-register (bias already in acc)
                unsigned short hv[4];
#pragma unroll
                for (int r = 0; r < 4; ++r) {
                    float cn = sigm(acc[1][r]) * cst[r] + sigm(acc[0][r]) * tanh_f(acc[2][r]);
                    cst[r] = cn;
                    hv[r] = f2bf(sigm(acc[3][r]) * tanh_f(cn));
                }
                unsigned long long d = (unsigned long long)hv[0]
                                     | ((unsigned long long)hv[1] << 16)
                                     | ((unsigned long long)hv[2] << 32)
                                     | ((unsigned long long)hv[3] << 48);
                unsigned short* hp = hsc + ((size_t)t * 16 + l16) * HID
                                   + U0 + wave * 16 + quad * 4;
                if (fast) store_l2_x2(hp, d);
                else      store_coherent_x2(hp, d);
            }
            __syncthreads();             // all 4 waves' stores ack'd before flag
            if (tid == 0) {
                if (fast) store_u32_nowait_l2(myflag, (unsigned)(t + 1));
                else      store_u32_nowait(myflag, (unsigned)(t + 1));
            }
        }
    } else {
        // =============== MLP role (R4 verbatim) ===============
        const int mc  = clust;
        const int m   = sub;
        const int B0  = mc * 16;
        const unsigned* peer = flags + (mc * 8 + (lane & 7)) * 16;
        const unsigned short* hsc = hs + (size_t)mc * S_LEN * 16 * HID;
        const int sm = tid >> 4;
        const int sc = tid & 15;

        for (int t = m; t < S_LEN; t += 8) {
            if (wave == 0) {
                for (;;) {
                    unsigned v = ~0u;
                    if (lane < 8) v = fast ? load_u32_l2(peer) : load_u32_coherent(peer);
                    if (__ballot(v >= (unsigned)(t + 1)) == ~0ull) break;
                    __builtin_amdgcn_s_sleep(8);
                }
                if (lane == 0)
                    __hip_atomic_store(&rdy, (unsigned)(t + 1), __ATOMIC_RELAXED,
                                       __HIP_MEMORY_SCOPE_WORKGROUP);
            } else {
                while (__hip_atomic_load(&rdy, __ATOMIC_RELAXED,
                                         __HIP_MEMORY_SCOPE_WORKGROUP) < (unsigned)(t + 1))
                    __builtin_amdgcn_s_sleep(8);
            }
            {
                const unsigned short* src = hsc + ((size_t)t * 16 + sm) * HID + sc * 32;
                unsigned short* dst = At + sm * 552 + sc * 32;
                uint4 a0, a1, a2, a3;
                if (fast) load4_l2(src, a0, a1, a2, a3);
                else      load4_coherent(src, a0, a1, a2, a3);
                *(uint4*)(dst)      = a0;
                *(uint4*)(dst + 8)  = a1;
                *(uint4*)(dst + 16) = a2;
                *(uint4*)(dst + 24) = a3;
            }
            __syncthreads();

            f32x4 a1[4];
#pragma unroll
            for (int nt = 0; nt < 4; ++nt) a1[nt] = (f32x4){0.f, 0.f, 0.f, 0.f};
#pragma unroll
            for (int kk = 0; kk < 16; ++kk) {
                bf16x8 a = __builtin_bit_cast(
                    bf16x8, *(const uint4*)(At + l16 * 552 + kk * 32 + quad * 8));
#pragma unroll
                for (int nt = 0; nt < 4; ++nt) {
                    int n = wave * 64 + nt * 16 + l16;
                    bf16x8 b = __builtin_bit_cast(
                        bf16x8, *(const uint4*)(w1b + (size_t)n * 512 + kk * 32 + quad * 8));
                    a1[nt] = __builtin_amdgcn_mfma_f32_16x16x32_bf16(a, b, a1[nt], 0, 0, 0);
                }
            }
#pragma unroll
            for (int nt = 0; nt < 4; ++nt) {
                int n = wave * 64 + nt * 16 + l16;
                float bv = b1[n];
#pragma unroll
                for (int r = 0; r < 4; ++r)
                    hid[(quad * 4 + r) * 264 + n] = f2bf(fmaxf(a1[nt][r] + bv, 0.f));
            }
            __syncthreads();
            if (wave == 0) {
                f32x4 a2[2];
                a2[0] = (f32x4){0.f, 0.f, 0.f, 0.f};
                a2[1] = (f32x4){0.f, 0.f, 0.f, 0.f};
#pragma unroll
                for (int kk = 0; kk < 8; ++kk) {
                    bf16x8 a = __builtin_bit_cast(
                        bf16x8, *(const uint4*)(hid + l16 * 264 + kk * 32 + quad * 8));
#pragma unroll
                    for (int nt = 0; nt < 2; ++nt) {
                        int n = nt * 16 + l16;
                        bf16x8 b;
                        if (n < NCLS) {
                            b = __builtin_bit_cast(
                                bf16x8, *(const uint4*)(w2b + (size_t)n * 256 + kk * 32 + quad * 8));
                        } else {
                            uint4 z; z.x = z.y = z.z = z.w = 0u;
                            b = __builtin_bit_cast(bf16x8, z);
                        }
                        a2[nt] = __builtin_amdgcn_mfma_f32_16x16x32_bf16(a, b, a2[nt], 0, 0, 0);
                    }
                }
#pragma unroll
                for (int nt = 0; nt < 2; ++nt) {
                    int n = nt * 16 + l16;
                    if (n < NCLS) {
                        float bv = b2[n];
#pragma unroll
                        for (int r = 0; r < 4; ++r)
                            lg[(quad * 4 + r) * 24 + n] = a2[nt][r] + bv;
                    }
                }
            }
            __syncthreads();
            if (tid < 16) {
                float v[NCLS];
                float mx = -3.4e38f;
#pragma unroll
                for (int c = 0; c < NCLS; ++c) { v[c] = lg[tid * 24 + c]; mx = fmaxf(mx, v[c]); }
                float s = 0.f;
#pragma unroll
                for (int c = 0; c < NCLS; ++c) s += __expf(v[c] - mx);
                float lse = mx + __logf(s);
                float* orow = out + ((size_t)(B0 + tid) * S_LEN + t) * NCLS;
#pragma unroll
                for (int c = 0; c < NCLS; ++c) orow[c] = v[c] - lse;
            }
            __syncthreads();
        }
    }
}

// ============================================================================
// FALLBACK (small ws): unchanged. 384 wgs, 16x16 LSTM + 16x8 MLP,
// 16-slot ring + done backpressure.
// ============================================================================
__global__ __launch_bounds__(256, 2) void lstm_fused_kernel(
    const float* __restrict__ x, const float* __restrict__ w_ih,
    const float* __restrict__ w_hh, const float* __restrict__ b_ih,
    const float* __restrict__ b_hh, const unsigned short* __restrict__ w1b,
    const float* __restrict__ b1, const unsigned short* __restrict__ w2b,
    const float* __restrict__ b2, float* __restrict__ out,
    unsigned short* __restrict__ hb, unsigned* __restrict__ flags,
    unsigned* __restrict__ done)
{
    const int tid  = threadIdx.x;
    const int wave = tid >> 6;
    const int lane = tid & 63;
    const int quad = lane >> 4;
    const int l16  = lane & 15;
    const int wg   = blockIdx.x;

    __shared__ __align__(16) unsigned short At[16 * 552];
    __shared__ float zb[16 * 132];
    __shared__ __align__(16) unsigned short hid[16 * 264];
    __shared__ float lg[16 * 24];
    __shared__ unsigned rdy;
    if (tid == 0) rdy = 0u;
    __syncthreads();

    if (wg < 256) {
        const int clust = (wg & 7) * 2 + (wg >= 128 ? 1 : 0);
        const int wic   = (wg >> 3) & 15;
        const int B0    = clust * 16;
        const int U0    = wic * 32;

        bf16x8 bB[2][17];
#pragma unroll
        for (int tl = 0; tl < 2; ++tl) {
            const int row = wave * 512 + U0 + tl * 16 + l16;
            const float* wrow = w_hh + (size_t)row * HID;
#pragma unroll
            for (int kk = 0; kk < 16; ++kk) {
                const float* p = wrow + kk * 32 + quad * 8;
                bf16x8 v;
#pragma unroll
                for (int j = 0; j < 8; ++j) v[j] = (short)f2bf(p[j]);
                bB[tl][kk] = v;
            }
            const float* irow = w_ih + (size_t)row * FEAT;
            bf16x8 v;
#pragma unroll
            for (int j = 0; j < 8; ++j) {
                int ftr = quad * 8 + j;
                v[j] = (ftr < FEAT) ? (short)f2bf(irow[ftr]) : (short)0;
            }
            bB[tl][16] = v;
        }

        const int gb = tid >> 4;
        const int gu = tid & 15;
        float bias[2][4];
#pragma unroll
        for (int uu = 0; uu < 2; ++uu)
#pragma unroll
            for (int g = 0; g < 4; ++g) {
                int r = g * 512 + U0 + 2 * gu + uu;
                bias[uu][g] = b_ih[r] + b_hh[r];
            }
        float cst[2] = {0.f, 0.f};

        const int sm = tid >> 4;
        const int sc = tid & 15;
        unsigned short* hbc = hb + (size_t)clust * DRING * 16 * HID;
        unsigned* myflag = flags + (clust * 16 + wic) * 16;
        const unsigned* peer = flags + (clust * 16 + (lane & 15)) * 16;

        for (int t = 0; t < S_LEN; ++t) {
            {
                unsigned pk = 0u;
                if (sc <= 12) {
                    float2 xv = *(const float2*)(x + ((size_t)(B0 + sm) * S_LEN + t) * FEAT + sc * 2);
                    pk = (unsigned)f2bf(xv.x) | ((unsigned)f2bf(xv.y) << 16);
                }
                *(unsigned*)(At + sm * 552 + 512 + sc * 2) = pk;
            }
            if (t > 0) {
                if (wave == 0) {
                    if (t >= DRING && lane == 0) {
                        const unsigned* dn = done + (clust * 8 + (t & 7)) * 16;
                        while (load_u32_coherent(dn) < (unsigned)(t - (DRING - 1)))
                            __builtin_amdgcn_s_sleep(8);
                    }
                    for (;;) {
                        unsigned v = load_u32_coherent(peer);
                        if (__ballot(v >= (unsigned)t) == ~0ull) break;
                        __builtin_amdgcn_s_sleep(1);
                    }
                    if (lane == 0)
                        __hip_atomic_store(&rdy, (unsigned)t, __ATOMIC_RELAXED,
                                           __HIP_MEMORY_SCOPE_WORKGROUP);
                } else {
                    while (__hip_atomic_load(&rdy, __ATOMIC_RELAXED,
                                             __HIP_MEMORY_SCOPE_WORKGROUP) < (unsigned)t)
                        __builtin_amdgcn_s_sleep(1);
                }
                const unsigned short* src =
                    hbc + ((t - 1) & (DRING - 1)) * 16 * HID + sm * HID + sc * 32;
                unsigned short* dst = At + sm * 552 + sc * 32;
                uint4 a0, a1, a2, a3;
                load4_coherent(src, a0, a1, a2, a3);
                *(uint4*)(dst)      = a0;
                *(uint4*)(dst + 8)  = a1;
                *(uint4*)(dst + 16) = a2;
                *(uint4*)(dst + 24) = a3;
            }
            __syncthreads();

            f32x4 acc0 = {0.f, 0.f, 0.f, 0.f};
            f32x4 acc1 = {0.f, 0.f, 0.f, 0.f};
            const unsigned short* arow = At + l16 * 552 + quad * 8;
            if (t > 0) {
#pragma unroll
                for (int kk = 0; kk < 17; ++kk) {
                    bf16x8 a = __builtin_bit_cast(bf16x8, *(const uint4*)(arow + kk * 32));
                    acc0 = __builtin_amdgcn_mfma_f32_16x16x32_bf16(a, bB[0][kk], acc0, 0, 0, 0);
                    acc1 = __builtin_amdgcn_mfma_f32_16x16x32_bf16(a, bB[1][kk], acc1, 0, 0, 0);
                }
            } else {
                bf16x8 a = __builtin_bit_cast(bf16x8, *(const uint4*)(arow + 16 * 32));
                acc0 = __builtin_amdgcn_mfma_f32_16x16x32_bf16(a, bB[0][16], acc0, 0, 0, 0);
                acc1 = __builtin_amdgcn_mfma_f32_16x16x32_bf16(a, bB[1][16], acc1, 0, 0, 0);
            }
#pragma unroll
            for (int r = 0; r < 4; ++r) {
                zb[(quad * 4 + r) * 132 + wave * 32 + l16]      = acc0[r];
                zb[(quad * 4 + r) * 132 + wave * 32 + 16 + l16] = acc1[r];
            }
            __syncthreads();

            {
                const float* zrow = zb + gb * 132;
                unsigned short hv2[2];
#pragma unroll
                for (int uu = 0; uu < 2; ++uu) {
                    int u = 2 * gu + uu;
                    float zi = zrow[u]      + bias[uu][0];
                    float zf = zrow[32 + u] + bias[uu][1];
                    float zg = zrow[64 + u] + bias[uu][2];
                    float zo = zrow[96 + u] + bias[uu][3];
                    float cn = sigm(zf) * cst[uu] + sigm(zi) * tanh_f(zg);
                    cst[uu] = cn;
                    hv2[uu] = f2bf(sigm(zo) * tanh_f(cn));
                }
                unsigned short* hp =
                    hbc + (t & (DRING - 1)) * 16 * HID + gb * HID + U0 + 2 * gu;
                store_coherent(hp, (unsigned)hv2[0] | ((unsigned)hv2[1] << 16));
            }
            __syncthreads();
            if (tid == 0) store_u32_nowait(myflag, (unsigned)(t + 1));
        }
    } else {
        const int mwg  = wg - 256;
        const int mc   = mwg >> 3;
        const int m    = mwg & 7;
        const int B0   = mc * 16;
        unsigned* mydone = done + (mc * 8 + m) * 16;
        const unsigned* peer = flags + (mc * 16 + (lane & 15)) * 16;
        const unsigned short* hbc = hb + (size_t)mc * DRING * 16 * HID;
        const int sm = tid >> 4;
        const int sc = tid & 15;

        for (int t = m; t < S_LEN; t += 8) {
            if (wave == 0) {
                for (;;) {
                    unsigned v = load_u32_coherent(peer);
                    if (__ballot(v >= (unsigned)(t + 1)) == ~0ull) break;
                    __builtin_amdgcn_s_sleep(8);
                }
                if (lane == 0)
                    __hip_atomic_store(&rdy, (unsigned)(t + 1), __ATOMIC_RELAXED,
                                       __HIP_MEMORY_SCOPE_WORKGROUP);
            } else {
                while (__hip_atomic_load(&rdy, __ATOMIC_RELAXED,
                                         __HIP_MEMORY_SCOPE_WORKGROUP) < (unsigned)(t + 1))
                    __builtin_amdgcn_s_sleep(8);
            }
            {
                const unsigned short* src =
                    hbc + (t & (DRING - 1)) * 16 * HID + sm * HID + sc * 32;
                unsigned short* dst = At + sm * 552 + sc * 32;
                uint4 a0, a1, a2, a3;
                load4_coherent(src, a0, a1, a2, a3);
                *(uint4*)(dst)      = a0;
                *(uint4*)(dst + 8)  = a1;
                *(uint4*)(dst + 16) = a2;
                *(uint4*)(dst + 24) = a3;
            }
            __syncthreads();
            if (tid == 0) store_u32_nowait(mydone, (unsigned)(t + 1));

            f32x4 a1[4];
#pragma unroll
            for (int nt = 0; nt < 4; ++nt) a1[nt] = (f32x4){0.f, 0.f, 0.f, 0.f};
#pragma unroll
            for (int kk = 0; kk < 16; ++kk) {
                bf16x8 a = __builtin_bit_cast(
                    bf16x8, *(const uint4*)(At + l16 * 552 + kk * 32 + quad * 8));
#pragma unroll
                for (int nt = 0; nt < 4; ++nt) {
                    int n = wave * 64 + nt * 16 + l16;
                    bf16x8 b = __builtin_bit_cast(
                        bf16x8, *(const uint4*)(w1b + (size_t)n * 512 + kk * 32 + quad * 8));
                    a1[nt] = __builtin_amdgcn_mfma_f32_16x16x32_bf16(a, b, a1[nt], 0, 0, 0);
                }
            }
#pragma unroll
            for (int nt = 0; nt < 4; ++nt) {
                int n = wave * 64 + nt * 16 + l16;
                float bv = b1[n];
#pragma unroll
                for (int r = 0; r < 4; ++r)
                    hid[(quad * 4 + r) * 264 + n] = f2bf(fmaxf(a1[nt][r] + bv, 0.f));
            }
            __syncthreads();
            if (wave == 0) {
                f32x4 a2[2];
                a2[0] = (f32x4){0.f, 0.f, 0.f, 0.f};
                a2[1] = (f32x4){0.f, 0.f, 0.f, 0.f};
#pragma unroll
                for (int kk = 0; kk < 8; ++kk) {
                    bf16x8 a = __builtin_bit_cast(
                        bf16x8, *(const uint4*)(hid + l16 * 264 + kk * 32 + quad * 8));
#pragma unroll
                    for (int nt = 0; nt < 2; ++nt) {
                        int n = nt * 16 + l16;
                        bf16x8 b;
                        if (n < NCLS) {
                            b = __builtin_bit_cast(
                                bf16x8, *(const uint4*)(w2b + (size_t)n * 256 + kk * 32 + quad * 8));
                        } else {
                            uint4 z; z.x = z.y = z.z = z.w = 0u;
                            b = __builtin_bit_cast(bf16x8, z);
                        }
                        a2[nt] = __builtin_amdgcn_mfma_f32_16x16x32_bf16(a, b, a2[nt], 0, 0, 0);
                    }
                }
#pragma unroll
                for (int nt = 0; nt < 2; ++nt) {
                    int n = nt * 16 + l16;
                    if (n < NCLS) {
                        float bv = b2[n];
#pragma unroll
                        for (int r = 0; r < 4; ++r)
                            lg[(quad * 4 + r) * 24 + n] = a2[nt][r] + bv;
                    }
                }
            }
            __syncthreads();
            if (tid < 16) {
                float v[NCLS];
                float mx = -3.4e38f;
#pragma unroll
                for (int c = 0; c < NCLS; ++c) { v[c] = lg[tid * 24 + c]; mx = fmaxf(mx, v[c]); }
                float s = 0.f;
#pragma unroll
                for (int c = 0; c < NCLS; ++c) s += __expf(v[c] - mx);
                float lse = mx + __logf(s);
                float* orow = out + ((size_t)(B0 + tid) * S_LEN + t) * NCLS;
#pragma unroll
                for (int c = 0; c < NCLS; ++c) orow[c] = v[c] - lse;
            }
            __syncthreads();
        }
    }
}

extern "C" void kernel_launch(void* const* d_in, const int* in_sizes, int n_in,
                              void* d_out, int out_size, void* d_ws, size_t ws_size,
                              hipStream_t stream) {
    const float* x    = (const float*)d_in[0];
    const float* w_ih = (const float*)d_in[1];
    const float* w_hh = (const float*)d_in[2];
    const float* b_ih = (const float*)d_in[3];
    const float* b_hh = (const float*)d_in[4];
    const float* w1   = (const float*)d_in[5];
    const float* b1   = (const float*)d_in[6];
    const float* w2   = (const float*)d_in[7];
    const float* b2   = (const float*)d_in[8];
    char* ws = (char*)d_ws;

    const size_t HS_BYTES = (size_t)16 * S_LEN * 16 * HID * 2;   // 128 MB
    const size_t NEED_BIG = HS_BYTES + 8192 + 262144 + 10240;

    if (ws_size >= NEED_BIG) {
        unsigned short* hsb   = (unsigned short*)ws;
        unsigned*       flags = (unsigned*)(ws + HS_BYTES);
        unsigned short* w1b   = (unsigned short*)(ws + HS_BYTES + 8192);
        unsigned short* w2b   = (unsigned short*)(ws + HS_BYTES + 8192 + 262144);
        prep_kernel<<<512, 256, 0, stream>>>(w1, w2, w1b, w2b, flags, 2048);
        lstm_big_kernel<<<256, 256, 0, stream>>>(x, w_ih, w_hh, b_ih, b_hh,
                                                 w1b, b1, w2b, b2,
                                                 (float*)d_out, hsb, flags);
    } else {
        unsigned short* hb    = (unsigned short*)ws;
        unsigned*       flags = (unsigned*)(ws + 4194304);
        unsigned*       done  = (unsigned*)(ws + 4194304 + 16384);
        unsigned short* w1b   = (unsigned short*)(ws + 4194304 + 16384 + 8192);
        unsigned short* w2b   = (unsigned short*)(ws + 4194304 + 16384 + 8192 + 262144);
        prep_kernel<<<512, 256, 0, stream>>>(w1, w2, w1b, w2b, flags, 6144);
        lstm_fused_kernel<<<384, 256, 0, stream>>>(x, w_ih, w_hh, b_ih, b_hh,
                                                   w1b, b1, w2b, b2,
                                                   (float*)d_out, hb, flags, done);
    }
}

// Round 8
// 1896.145 us; speedup vs baseline: 1.1526x; 1.0896x over previous
//
#include <hip/hip_runtime.h>

#define S_LEN 512
#define HID   512
#define FEAT  26
#define NCLS  20
#define DRING 16

typedef short bf16x8 __attribute__((ext_vector_type(8)));
typedef float f32x4  __attribute__((ext_vector_type(4)));

__device__ __forceinline__ unsigned short f2bf(float f) {   // RNE
    unsigned u = __builtin_bit_cast(unsigned, f);
    unsigned r = (u + 0x7FFFu + ((u >> 16) & 1u)) >> 16;
    return (unsigned short)r;
}
__device__ __forceinline__ float sigm(float x) { return 1.f / (1.f + __expf(-x)); }
__device__ __forceinline__ float tanh_f(float x) {
    float xc = fminf(fmaxf(x, -15.f), 15.f);
    float t = __expf(-2.f * xc);
    return (1.f - t) / (1.f + t);
}

// ---------------- system-scope (sc0 sc1, MALL) helpers ----------------
__device__ __forceinline__ void load4_coherent(const unsigned short* p,
                                               uint4& a0, uint4& a1, uint4& a2, uint4& a3) {
    asm volatile(
        "global_load_dwordx4 %0, %4, off sc0 sc1\n\t"
        "global_load_dwordx4 %1, %5, off sc0 sc1\n\t"
        "global_load_dwordx4 %2, %6, off sc0 sc1\n\t"
        "global_load_dwordx4 %3, %7, off sc0 sc1\n\t"
        "s_waitcnt vmcnt(0)"
        : "=&v"(a0), "=&v"(a1), "=&v"(a2), "=&v"(a3)
        : "v"(p), "v"(p + 8), "v"(p + 16), "v"(p + 24)
        : "memory");
}
__device__ __forceinline__ void store_coherent(unsigned short* p, unsigned d) {
    asm volatile(
        "global_store_dword %0, %1, off sc0 sc1\n\t"
        "s_waitcnt vmcnt(0)"
        :: "v"(p), "v"(d) : "memory");
}
__device__ __forceinline__ void store_coherent_x2(unsigned short* p, unsigned long long d) {
    asm volatile(
        "global_store_dwordx2 %0, %1, off sc0 sc1\n\t"
        "s_waitcnt vmcnt(0)"
        :: "v"(p), "v"(d) : "memory");
}
__device__ __forceinline__ void store_u32_nowait(unsigned* p, unsigned d) {
    asm volatile("global_store_dword %0, %1, off sc0 sc1" :: "v"(p), "v"(d) : "memory");
}
__device__ __forceinline__ unsigned load_u32_coherent(const unsigned* p) {
    unsigned v;
    asm volatile("global_load_dword %0, %1, off sc0 sc1\n\ts_waitcnt vmcnt(0)"
                 : "=v"(v) : "v"(p) : "memory");
    return v;
}
__device__ __forceinline__ void store_u32_sys_wait(unsigned* p, unsigned d) {
    asm volatile("global_store_dword %0, %1, off sc0 sc1\n\ts_waitcnt vmcnt(0)"
                 :: "v"(p), "v"(d) : "memory");
}
// 2x contiguous 16B system-scope loads, NO wait (caller manages vmcnt).
__device__ __forceinline__ void load2_nw_sys(const unsigned short* p, uint4& a0, uint4& a1) {
    asm volatile(
        "global_load_dwordx4 %0, %2, off sc0 sc1\n\t"
        "global_load_dwordx4 %1, %3, off sc0 sc1"
        : "=&v"(a0), "=&v"(a1) : "v"(p), "v"(p + 8) : "memory");
}

// ---------------- XCD-local (sc0 only, per-XCD L2) helpers ----------------
__device__ __forceinline__ void load4_l2(const unsigned short* p,
                                         uint4& a0, uint4& a1, uint4& a2, uint4& a3) {
    asm volatile(
        "global_load_dwordx4 %0, %4, off sc0\n\t"
        "global_load_dwordx4 %1, %5, off sc0\n\t"
        "global_load_dwordx4 %2, %6, off sc0\n\t"
        "global_load_dwordx4 %3, %7, off sc0\n\t"
        "s_waitcnt vmcnt(0)"
        : "=&v"(a0), "=&v"(a1), "=&v"(a2), "=&v"(a3)
        : "v"(p), "v"(p + 8), "v"(p + 16), "v"(p + 24)
        : "memory");
}
__device__ __forceinline__ void store_l2_x2(unsigned short* p, unsigned long long d) {
    asm volatile(
        "global_store_dwordx2 %0, %1, off sc0\n\t"
        "s_waitcnt vmcnt(0)"
        :: "v"(p), "v"(d) : "memory");
}
__device__ __forceinline__ void store_u32_nowait_l2(unsigned* p, unsigned d) {
    asm volatile("global_store_dword %0, %1, off sc0" :: "v"(p), "v"(d) : "memory");
}
__device__ __forceinline__ unsigned load_u32_l2(const unsigned* p) {
    unsigned v;
    asm volatile("global_load_dword %0, %1, off sc0\n\ts_waitcnt vmcnt(0)"
                 : "=v"(v) : "v"(p) : "memory");
    return v;
}
// 2x contiguous 16B L2-scope loads, NO wait (caller manages vmcnt).
__device__ __forceinline__ void load2_nw_l2(const unsigned short* p, uint4& a0, uint4& a1) {
    asm volatile(
        "global_load_dwordx4 %0, %2, off sc0\n\t"
        "global_load_dwordx4 %1, %3, off sc0"
        : "=&v"(a0), "=&v"(a1) : "v"(p), "v"(p + 8) : "memory");
}

// zero sync words, convert w1/w2 fp32 -> bf16
__global__ void prep_kernel(const float* __restrict__ w1, const float* __restrict__ w2,
                            unsigned short* __restrict__ w1b, unsigned short* __restrict__ w2b,
                            unsigned* __restrict__ syncw, int nclear) {
    int i = blockIdx.x * 256 + threadIdx.x;
    if (i < nclear) syncw[i] = 0u;
    if (i < 256 * 512) w1b[i] = f2bf(w1[i]);
    if (i < NCLS * 256) w2b[i] = f2bf(w2[i]);
}

// ============================================================================
// BIG-WS PATH: 256 wgs on 256 CUs (1 wg/CU).
// Round-8 = Round-4 verbatim (best verified: 1945us). Split-staging pipeline:
//  - split h-exchange: g0 = producers 0-3 (k-slices 0-7), g1 = producers 4-7
//    (k-slices 8-15). Poll gates on g0 only, g1 flag values captured in the
//    same poll loads. g1 data loads are issued no-wait and stay in flight
//    ACROSS a raw s_barrier (lgkmcnt-only drain) while MFMA x+k0..7 runs.
//  - gate bias folded into MFMA C-init (acc starts at bias, broadcast over n).
//  - single per-producer flag published by tid0 after the closing barrier
//    (R5/R6 lesson: any per-wave flag scheme regresses).
//  - x staged cooperatively at loop top (R7 lesson: deferring its wait into
//    the poll serializes it into every poll iteration's vmcnt(0)).
// ============================================================================
__global__ __launch_bounds__(256, 1) void lstm_big_kernel(
    const float* __restrict__ x,
    const float* __restrict__ w_ih,
    const float* __restrict__ w_hh,
    const float* __restrict__ b_ih,
    const float* __restrict__ b_hh,
    const unsigned short* __restrict__ w1b,
    const float* __restrict__ b1,
    const unsigned short* __restrict__ w2b,
    const float* __restrict__ b2,
    float* __restrict__ out,
    unsigned short* __restrict__ hs,   // [16][S][16][HID] bf16
    unsigned* __restrict__ flags)      // [16][8] x 16-dword stride; dw0=flag, dw8/dw9=xcc
{
    const int tid  = threadIdx.x;
    const int wave = tid >> 6;
    const int lane = tid & 63;
    const int quad = lane >> 4;
    const int l16  = lane & 15;

    // ---- XCD-affinity role remap ----
    const int  bx      = blockIdx.x;
    const int  xasm    = bx & 7;          // assumed XCD under round-robin
    const int  kslt    = bx >> 3;         // slot within assumed XCD (0..31)
    const bool is_lstm = (kslt < 16);
    const int  ksub    = is_lstm ? kslt : (kslt - 16);
    const int  clust   = xasm * 2 + (ksub >> 3);
    const int  sub     = ksub & 7;        // wic (LSTM) or m (MLP)

    __shared__ __align__(16) unsigned short At[16 * 552];
    __shared__ __align__(16) unsigned short hid[16 * 264];  // MLP only
    __shared__ float lg[16 * 24];                            // MLP only
    __shared__ unsigned rdy;
    __shared__ unsigned fastf;
    if (tid == 0) rdy = 0u;

    // ---- runtime same-XCD verification (one-time) ----
    {
        unsigned xcc;
        asm volatile("s_getreg_b32 %0, hwreg(HW_REG_XCC_ID)" : "=s"(xcc));
        if (tid == 0) {
            unsigned* slot = flags + (clust * 8 + sub) * 16 + (is_lstm ? 8 : 9);
            store_u32_sys_wait(slot, (xcc & 0xFu) + 1u);
        }
        if (wave == 0) {
            const unsigned* ps = flags + (clust * 8 + (lane & 7)) * 16 + ((lane & 8) ? 9 : 8);
            unsigned myx = 1u;
            for (;;) {
                unsigned v = 1u;
                if (lane < 16) v = load_u32_coherent(ps);
                if (__ballot(v != 0u) == ~0ull) { myx = v; break; }
                __builtin_amdgcn_s_sleep(2);
            }
            unsigned ref = __shfl(myx, 0);
            bool eq = (lane >= 16) || (myx == ref);
            if (tid == 0) fastf = (__ballot(eq) == ~0ull) ? 1u : 0u;
        }
    }
    __syncthreads();
    const bool fast = (fastf != 0u);

    if (is_lstm) {
        // =============== LSTM role ===============
        const int wic = sub;
        const int B0  = clust * 16;
        const int U0  = wic * 64;

        // Weights as the MFMA *A* operand: lane holds row (unit = U0+wave*16+l16)
        // for all 4 gates, k-slice = kk*32 + quad*8.
        bf16x8 bB[4][17];           // kk 0..15 = w_hh, kk 16 = w_ih
#pragma unroll
        for (int g = 0; g < 4; ++g) {
            const int row = g * 512 + U0 + wave * 16 + l16;
            const float* wrow = w_hh + (size_t)row * HID;
#pragma unroll
            for (int kk = 0; kk < 16; ++kk) {
                const float* p = wrow + kk * 32 + quad * 8;
                bf16x8 v;
#pragma unroll
                for (int j = 0; j < 8; ++j) v[j] = (short)f2bf(p[j]);
                bB[g][kk] = v;
            }
            const float* irow = w_ih + (size_t)row * FEAT;
            bf16x8 v;
#pragma unroll
            for (int j = 0; j < 8; ++j) {
                int ftr = quad * 8 + j;
                v[j] = (ftr < FEAT) ? (short)f2bf(irow[ftr]) : (short)0;
            }
            bB[g][16] = v;
        }

        // D[m=quad*4+r][n=batch l16]; bias per lane for units quad*4+r, folded
        // into the MFMA C-init (broadcast over n is exactly the D layout).
        f32x4 biasv[4];
#pragma unroll
        for (int g = 0; g < 4; ++g)
#pragma unroll
            for (int r = 0; r < 4; ++r) {
                int rr = g * 512 + U0 + wave * 16 + quad * 4 + r;
                biasv[g][r] = b_ih[rr] + b_hh[rr];
            }
        float cst[4] = {0.f, 0.f, 0.f, 0.f};   // c-state: batch l16, units quad*4+r

        const int sm = tid >> 4;
        const int sc = tid & 15;
        unsigned short* hsc = hs + (size_t)clust * S_LEN * 16 * HID;
        unsigned* myflag = flags + (clust * 8 + wic) * 16;
        const unsigned* peer = flags + (clust * 8 + (lane & 7)) * 16;

        for (int t = 0; t < S_LEN; ++t) {
            {   // stage x_t (off critical path)
                unsigned pk = 0u;
                if (sc <= 12) {
                    float2 xv = *(const float2*)(x + ((size_t)(B0 + sm) * S_LEN + t) * FEAT + sc * 2);
                    pk = (unsigned)f2bf(xv.x) | ((unsigned)f2bf(xv.y) << 16);
                }
                *(unsigned*)(At + sm * 552 + 512 + sc * 2) = pk;
            }

            f32x4 acc[4];
#pragma unroll
            for (int g = 0; g < 4; ++g) acc[g] = biasv[g];

            if (t > 0) {
                const unsigned tt = (unsigned)t;
                // poll all 8 flags; gate on g0 (producers 0-3), capture g1
                unsigned long long bal;
                for (;;) {
                    unsigned v = ~0u;
                    if (lane < 8) v = fast ? load_u32_l2(peer) : load_u32_coherent(peer);
                    bal = __ballot(v >= tt);
                    if ((bal & 0xFull) == 0xFull) break;
                    if (!fast) __builtin_amdgcn_s_sleep(1);
                }
                const bool g1ok = ((bal >> 4) & 0xFull) == 0xFull;

                // issue g0 staging loads (h cols 0..255), 32B/thread, no wait
                const unsigned short* srow = hsc + ((size_t)(t - 1) * 16 + sm) * HID;
                uint4 s0, s1, s2, s3;
                if (fast) load2_nw_l2(srow + sc * 16, s0, s1);
                else      load2_nw_sys(srow + sc * 16, s0, s1);

                if (!g1ok) {   // rare: finish waiting for producers 4-7
                    for (;;) {
                        unsigned v = ~0u;
                        if (lane >= 4 && lane < 8)
                            v = fast ? load_u32_l2(peer) : load_u32_coherent(peer);
                        unsigned long long b2_ = __ballot(v >= tt);
                        if (((b2_ >> 4) & 0xFull) == 0xFull) break;
                        if (!fast) __builtin_amdgcn_s_sleep(1);
                    }
                }
                asm volatile("s_waitcnt vmcnt(0)" ::: "memory");
                __builtin_amdgcn_sched_barrier(0);
                {   // LDS write g0
                    unsigned short* dst = At + sm * 552 + sc * 16;
                    *(uint4*)(dst)     = s0;
                    *(uint4*)(dst + 8) = s1;
                }
                // issue g1 staging loads (h cols 256..511) -- stay in flight
                // across the barrier, land during MFMA phase A
                if (fast) load2_nw_l2(srow + 256 + sc * 16, s2, s3);
                else      load2_nw_sys(srow + 256 + sc * 16, s2, s3);

                // barrier #1: LDS (g0 + x) visible; vmcnt NOT drained
                asm volatile("s_waitcnt lgkmcnt(0)" ::: "memory");
                __builtin_amdgcn_sched_barrier(0);
                __builtin_amdgcn_s_barrier();

                // MFMA phase A: x (kk16) + k-slices 0..7
                const unsigned short* arow = At + l16 * 552 + quad * 8;
                {
                    bf16x8 hx = __builtin_bit_cast(bf16x8, *(const uint4*)(arow + 16 * 32));
#pragma unroll
                    for (int g = 0; g < 4; ++g)
                        acc[g] = __builtin_amdgcn_mfma_f32_16x16x32_bf16(bB[g][16], hx, acc[g], 0, 0, 0);
                }
#pragma unroll
                for (int kk = 0; kk < 8; ++kk) {
                    bf16x8 h = __builtin_bit_cast(bf16x8, *(const uint4*)(arow + kk * 32));
#pragma unroll
                    for (int g = 0; g < 4; ++g)
                        acc[g] = __builtin_amdgcn_mfma_f32_16x16x32_bf16(bB[g][kk], h, acc[g], 0, 0, 0);
                }

                // g1 data arrived during phase A; write LDS, barrier #2
                asm volatile("s_waitcnt vmcnt(0)" ::: "memory");
                __builtin_amdgcn_sched_barrier(0);
                {
                    unsigned short* dst = At + sm * 552 + 256 + sc * 16;
                    *(uint4*)(dst)     = s2;
                    *(uint4*)(dst + 8) = s3;
                }
                asm volatile("s_waitcnt lgkmcnt(0)" ::: "memory");
                __builtin_amdgcn_sched_barrier(0);
                __builtin_amdgcn_s_barrier();

                // MFMA phase B: k-slices 8..15
#pragma unroll
                for (int kk = 8; kk < 16; ++kk) {
                    bf16x8 h = __builtin_bit_cast(bf16x8, *(const uint4*)(arow + kk * 32));
#pragma unroll
                    for (int g = 0; g < 4; ++g)
                        acc[g] = __builtin_amdgcn_mfma_f32_16x16x32_bf16(bB[g][kk], h, acc[g], 0, 0, 0);
                }
            } else {
                __syncthreads();   // x staged
                const unsigned short* arow = At + l16 * 552 + quad * 8;
                bf16x8 hx = __builtin_bit_cast(bf16x8, *(const uint4*)(arow + 16 * 32));
#pragma unroll
                for (int g = 0; g < 4; ++g)
                    acc[g] = __builtin_amdgcn_mfma_f32_16x16x32_bf16(bB[g][16], hx, acc[g], 0, 0, 0);
            }

            {   // gates fully in-register (bias already in acc)
                unsigned short hv[4];
#pragma unroll
                for (int r = 0; r < 4; ++r) {
                    float cn = sigm(acc[1][r]) * cst[r] + sigm(acc[0][r]) * tanh_f(acc[2][r]);
                    cst[r] = cn;
                    hv[r] = f2bf(sigm(acc[3][r]) * tanh_f(cn));
                }
                unsigned long long d = (unsigned long long)hv[0]
                                     | ((unsigned long long)hv[1] << 16)
                                     | ((unsigned long long)hv[2] << 32)
                                     | ((unsigned long long)hv[3] << 48);
                unsigned short* hp = hsc + ((size_t)t * 16 + l16) * HID
                                   + U0 + wave * 16 + quad * 4;
                if (fast) store_l2_x2(hp, d);
                else      store_coherent_x2(hp, d);
            }
            __syncthreads();             // all 4 waves' stores ack'd before flag
            if (tid == 0) {
                if (fast) store_u32_nowait_l2(myflag, (unsigned)(t + 1));
                else      store_u32_nowait(myflag, (unsigned)(t + 1));
            }
        }
    } else {
        // =============== MLP role ===============
        const int mc  = clust;
        const int m   = sub;
        const int B0  = mc * 16;
        const unsigned* peer = flags + (mc * 8 + (lane & 7)) * 16;
        const unsigned short* hsc = hs + (size_t)mc * S_LEN * 16 * HID;
        const int sm = tid >> 4;
        const int sc = tid & 15;

        for (int t = m; t < S_LEN; t += 8) {
            if (wave == 0) {
                for (;;) {
                    unsigned v = ~0u;
                    if (lane < 8) v = fast ? load_u32_l2(peer) : load_u32_coherent(peer);
                    if (__ballot(v >= (unsigned)(t + 1)) == ~0ull) break;
                    __builtin_amdgcn_s_sleep(8);
                }
                if (lane == 0)
                    __hip_atomic_store(&rdy, (unsigned)(t + 1), __ATOMIC_RELAXED,
                                       __HIP_MEMORY_SCOPE_WORKGROUP);
            } else {
                while (__hip_atomic_load(&rdy, __ATOMIC_RELAXED,
                                         __HIP_MEMORY_SCOPE_WORKGROUP) < (unsigned)(t + 1))
                    __builtin_amdgcn_s_sleep(8);
            }
            {
                const unsigned short* src = hsc + ((size_t)t * 16 + sm) * HID + sc * 32;
                unsigned short* dst = At + sm * 552 + sc * 32;
                uint4 a0, a1, a2, a3;
                if (fast) load4_l2(src, a0, a1, a2, a3);
                else      load4_coherent(src, a0, a1, a2, a3);
                *(uint4*)(dst)      = a0;
                *(uint4*)(dst + 8)  = a1;
                *(uint4*)(dst + 16) = a2;
                *(uint4*)(dst + 24) = a3;
            }
            __syncthreads();

            f32x4 a1[4];
#pragma unroll
            for (int nt = 0; nt < 4; ++nt) a1[nt] = (f32x4){0.f, 0.f, 0.f, 0.f};
#pragma unroll
            for (int kk = 0; kk < 16; ++kk) {
                bf16x8 a = __builtin_bit_cast(
                    bf16x8, *(const uint4*)(At + l16 * 552 + kk * 32 + quad * 8));
#pragma unroll
                for (int nt = 0; nt < 4; ++nt) {
                    int n = wave * 64 + nt * 16 + l16;
                    bf16x8 b = __builtin_bit_cast(
                        bf16x8, *(const uint4*)(w1b + (size_t)n * 512 + kk * 32 + quad * 8));
                    a1[nt] = __builtin_amdgcn_mfma_f32_16x16x32_bf16(a, b, a1[nt], 0, 0, 0);
                }
            }
#pragma unroll
            for (int nt = 0; nt < 4; ++nt) {
                int n = wave * 64 + nt * 16 + l16;
                float bv = b1[n];
#pragma unroll
                for (int r = 0; r < 4; ++r)
                    hid[(quad * 4 + r) * 264 + n] = f2bf(fmaxf(a1[nt][r] + bv, 0.f));
            }
            __syncthreads();
            if (wave == 0) {
                f32x4 a2[2];
                a2[0] = (f32x4){0.f, 0.f, 0.f, 0.f};
                a2[1] = (f32x4){0.f, 0.f, 0.f, 0.f};
#pragma unroll
                for (int kk = 0; kk < 8; ++kk) {
                    bf16x8 a = __builtin_bit_cast(
                        bf16x8, *(const uint4*)(hid + l16 * 264 + kk * 32 + quad * 8));
#pragma unroll
                    for (int nt = 0; nt < 2; ++nt) {
                        int n = nt * 16 + l16;
                        bf16x8 b;
                        if (n < NCLS) {
                            b = __builtin_bit_cast(
                                bf16x8, *(const uint4*)(w2b + (size_t)n * 256 + kk * 32 + quad * 8));
                        } else {
                            uint4 z; z.x = z.y = z.z = z.w = 0u;
                            b = __builtin_bit_cast(bf16x8, z);
                        }
                        a2[nt] = __builtin_amdgcn_mfma_f32_16x16x32_bf16(a, b, a2[nt], 0, 0, 0);
                    }
                }
#pragma unroll
                for (int nt = 0; nt < 2; ++nt) {
                    int n = nt * 16 + l16;
                    if (n < NCLS) {
                        float bv = b2[n];
#pragma unroll
                        for (int r = 0; r < 4; ++r)
                            lg[(quad * 4 + r) * 24 + n] = a2[nt][r] + bv;
                    }
                }
            }
            __syncthreads();
            if (tid < 16) {
                float v[NCLS];
                float mx = -3.4e38f;
#pragma unroll
                for (int c = 0; c < NCLS; ++c) { v[c] = lg[tid * 24 + c]; mx = fmaxf(mx, v[c]); }
                float s = 0.f;
#pragma unroll
                for (int c = 0; c < NCLS; ++c) s += __expf(v[c] - mx);
                float lse = mx + __logf(s);
                float* orow = out + ((size_t)(B0 + tid) * S_LEN + t) * NCLS;
#pragma unroll
                for (int c = 0; c < NCLS; ++c) orow[c] = v[c] - lse;
            }
            __syncthreads();
        }
    }
}

// ============================================================================
// FALLBACK (small ws): unchanged. 384 wgs, 16x16 LSTM + 16x8 MLP,
// 16-slot ring + done backpressure.
// ============================================================================
__global__ __launch_bounds__(256, 2) void lstm_fused_kernel(
    const float* __restrict__ x, const float* __restrict__ w_ih,
    const float* __restrict__ w_hh, const float* __restrict__ b_ih,
    const float* __restrict__ b_hh, const unsigned short* __restrict__ w1b,
    const float* __restrict__ b1, const unsigned short* __restrict__ w2b,
    const float* __restrict__ b2, float* __restrict__ out,
    unsigned short* __restrict__ hb, unsigned* __restrict__ flags,
    unsigned* __restrict__ done)
{
    const int tid  = threadIdx.x;
    const int wave = tid >> 6;
    const int lane = tid & 63;
    const int quad = lane >> 4;
    const int l16  = lane & 15;
    const int wg   = blockIdx.x;

    __shared__ __align__(16) unsigned short At[16 * 552];
    __shared__ float zb[16 * 132];
    __shared__ __align__(16) unsigned short hid[16 * 264];
    __shared__ float lg[16 * 24];
    __shared__ unsigned rdy;
    if (tid == 0) rdy = 0u;
    __syncthreads();

    if (wg < 256) {
        const int clust = (wg & 7) * 2 + (wg >= 128 ? 1 : 0);
        const int wic   = (wg >> 3) & 15;
        const int B0    = clust * 16;
        const int U0    = wic * 32;

        bf16x8 bB[2][17];
#pragma unroll
        for (int tl = 0; tl < 2; ++tl) {
            const int row = wave * 512 + U0 + tl * 16 + l16;
            const float* wrow = w_hh + (size_t)row * HID;
#pragma unroll
            for (int kk = 0; kk < 16; ++kk) {
                const float* p = wrow + kk * 32 + quad * 8;
                bf16x8 v;
#pragma unroll
                for (int j = 0; j < 8; ++j) v[j] = (short)f2bf(p[j]);
                bB[tl][kk] = v;
            }
            const float* irow = w_ih + (size_t)row * FEAT;
            bf16x8 v;
#pragma unroll
            for (int j = 0; j < 8; ++j) {
                int ftr = quad * 8 + j;
                v[j] = (ftr < FEAT) ? (short)f2bf(irow[ftr]) : (short)0;
            }
            bB[tl][16] = v;
        }

        const int gb = tid >> 4;
        const int gu = tid & 15;
        float bias[2][4];
#pragma unroll
        for (int uu = 0; uu < 2; ++uu)
#pragma unroll
            for (int g = 0; g < 4; ++g) {
                int r = g * 512 + U0 + 2 * gu + uu;
                bias[uu][g] = b_ih[r] + b_hh[r];
            }
        float cst[2] = {0.f, 0.f};

        const int sm = tid >> 4;
        const int sc = tid & 15;
        unsigned short* hbc = hb + (size_t)clust * DRING * 16 * HID;
        unsigned* myflag = flags + (clust * 16 + wic) * 16;
        const unsigned* peer = flags + (clust * 16 + (lane & 15)) * 16;

        for (int t = 0; t < S_LEN; ++t) {
            {
                unsigned pk = 0u;
                if (sc <= 12) {
                    float2 xv = *(const float2*)(x + ((size_t)(B0 + sm) * S_LEN + t) * FEAT + sc * 2);
                    pk = (unsigned)f2bf(xv.x) | ((unsigned)f2bf(xv.y) << 16);
                }
                *(unsigned*)(At + sm * 552 + 512 + sc * 2) = pk;
            }
            if (t > 0) {
                if (wave == 0) {
                    if (t >= DRING && lane == 0) {
                        const unsigned* dn = done + (clust * 8 + (t & 7)) * 16;
                        while (load_u32_coherent(dn) < (unsigned)(t - (DRING - 1)))
                            __builtin_amdgcn_s_sleep(8);
                    }
                    for (;;) {
                        unsigned v = load_u32_coherent(peer);
                        if (__ballot(v >= (unsigned)t) == ~0ull) break;
                        __builtin_amdgcn_s_sleep(1);
                    }
                    if (lane == 0)
                        __hip_atomic_store(&rdy, (unsigned)t, __ATOMIC_RELAXED,
                                           __HIP_MEMORY_SCOPE_WORKGROUP);
                } else {
                    while (__hip_atomic_load(&rdy, __ATOMIC_RELAXED,
                                             __HIP_MEMORY_SCOPE_WORKGROUP) < (unsigned)t)
                        __builtin_amdgcn_s_sleep(1);
                }
                const unsigned short* src =
                    hbc + ((t - 1) & (DRING - 1)) * 16 * HID + sm * HID + sc * 32;
                unsigned short* dst = At + sm * 552 + sc * 32;
                uint4 a0, a1, a2, a3;
                load4_coherent(src, a0, a1, a2, a3);
                *(uint4*)(dst)      = a0;
                *(uint4*)(dst + 8)  = a1;
                *(uint4*)(dst + 16) = a2;
                *(uint4*)(dst + 24) = a3;
            }
            __syncthreads();

            f32x4 acc0 = {0.f, 0.f, 0.f, 0.f};
            f32x4 acc1 = {0.f, 0.f, 0.f, 0.f};
            const unsigned short* arow = At + l16 * 552 + quad * 8;
            if (t > 0) {
#pragma unroll
                for (int kk = 0; kk < 17; ++kk) {
                    bf16x8 a = __builtin_bit_cast(bf16x8, *(const uint4*)(arow + kk * 32));
                    acc0 = __builtin_amdgcn_mfma_f32_16x16x32_bf16(a, bB[0][kk], acc0, 0, 0, 0);
                    acc1 = __builtin_amdgcn_mfma_f32_16x16x32_bf16(a, bB[1][kk], acc1, 0, 0, 0);
                }
            } else {
                bf16x8 a = __builtin_bit_cast(bf16x8, *(const uint4*)(arow + 16 * 32));
                acc0 = __builtin_amdgcn_mfma_f32_16x16x32_bf16(a, bB[0][16], acc0, 0, 0, 0);
                acc1 = __builtin_amdgcn_mfma_f32_16x16x32_bf16(a, bB[1][16], acc1, 0, 0, 0);
            }
#pragma unroll
            for (int r = 0; r < 4; ++r) {
                zb[(quad * 4 + r) * 132 + wave * 32 + l16]      = acc0[r];
                zb[(quad * 4 + r) * 132 + wave * 32 + 16 + l16] = acc1[r];
            }
            __syncthreads();

            {
                const float* zrow = zb + gb * 132;
                unsigned short hv2[2];
#pragma unroll
                for (int uu = 0; uu < 2; ++uu) {
                    int u = 2 * gu + uu;
                    float zi = zrow[u]      + bias[uu][0];
                    float zf = zrow[32 + u] + bias[uu][1];
                    float zg = zrow[64 + u] + bias[uu][2];
                    float zo = zrow[96 + u] + bias[uu][3];
                    float cn = sigm(zf) * cst[uu] + sigm(zi) * tanh_f(zg);
                    cst[uu] = cn;
                    hv2[uu] = f2bf(sigm(zo) * tanh_f(cn));
                }
                unsigned short* hp =
                    hbc + (t & (DRING - 1)) * 16 * HID + gb * HID + U0 + 2 * gu;
                store_coherent(hp, (unsigned)hv2[0] | ((unsigned)hv2[1] << 16));
            }
            __syncthreads();
            if (tid == 0) store_u32_nowait(myflag, (unsigned)(t + 1));
        }
    } else {
        const int mwg  = wg - 256;
        const int mc   = mwg >> 3;
        const int m    = mwg & 7;
        const int B0   = mc * 16;
        unsigned* mydone = done + (mc * 8 + m) * 16;
        const unsigned* peer = flags + (mc * 16 + (lane & 15)) * 16;
        const unsigned short* hbc = hb + (size_t)mc * DRING * 16 * HID;
        const int sm = tid >> 4;
        const int sc = tid & 15;

        for (int t = m; t < S_LEN; t += 8) {
            if (wave == 0) {
                for (;;) {
                    unsigned v = load_u32_coherent(peer);
                    if (__ballot(v >= (unsigned)(t + 1)) == ~0ull) break;
                    __builtin_amdgcn_s_sleep(8);
                }
                if (lane == 0)
                    __hip_atomic_store(&rdy, (unsigned)(t + 1), __ATOMIC_RELAXED,
                                       __HIP_MEMORY_SCOPE_WORKGROUP);
            } else {
                while (__hip_atomic_load(&rdy, __ATOMIC_RELAXED,
                                         __HIP_MEMORY_SCOPE_WORKGROUP) < (unsigned)(t + 1))
                    __builtin_amdgcn_s_sleep(8);
            }
            {
                const unsigned short* src =
                    hbc + (t & (DRING - 1)) * 16 * HID + sm * HID + sc * 32;
                unsigned short* dst = At + sm * 552 + sc * 32;
                uint4 a0, a1, a2, a3;
                load4_coherent(src, a0, a1, a2, a3);
                *(uint4*)(dst)      = a0;
                *(uint4*)(dst + 8)  = a1;
                *(uint4*)(dst + 16) = a2;
                *(uint4*)(dst + 24) = a3;
            }
            __syncthreads();
            if (tid == 0) store_u32_nowait(mydone, (unsigned)(t + 1));

            f32x4 a1[4];
#pragma unroll
            for (int nt = 0; nt < 4; ++nt) a1[nt] = (f32x4){0.f, 0.f, 0.f, 0.f};
#pragma unroll
            for (int kk = 0; kk < 16; ++kk) {
                bf16x8 a = __builtin_bit_cast(
                    bf16x8, *(const uint4*)(At + l16 * 552 + kk * 32 + quad * 8));
#pragma unroll
                for (int nt = 0; nt < 4; ++nt) {
                    int n = wave * 64 + nt * 16 + l16;
                    bf16x8 b = __builtin_bit_cast(
                        bf16x8, *(const uint4*)(w1b + (size_t)n * 512 + kk * 32 + quad * 8));
                    a1[nt] = __builtin_amdgcn_mfma_f32_16x16x32_bf16(a, b, a1[nt], 0, 0, 0);
                }
            }
#pragma unroll
            for (int nt = 0; nt < 4; ++nt) {
                int n = wave * 64 + nt * 16 + l16;
                float bv = b1[n];
#pragma unroll
                for (int r = 0; r < 4; ++r)
                    hid[(quad * 4 + r) * 264 + n] = f2bf(fmaxf(a1[nt][r] + bv, 0.f));
            }
            __syncthreads();
            if (wave == 0) {
                f32x4 a2[2];
                a2[0] = (f32x4){0.f, 0.f, 0.f, 0.f};
                a2[1] = (f32x4){0.f, 0.f, 0.f, 0.f};
#pragma unroll
                for (int kk = 0; kk < 8; ++kk) {
                    bf16x8 a = __builtin_bit_cast(
                        bf16x8, *(const uint4*)(hid + l16 * 264 + kk * 32 + quad * 8));
#pragma unroll
                    for (int nt = 0; nt < 2; ++nt) {
                        int n = nt * 16 + l16;
                        bf16x8 b;
                        if (n < NCLS) {
                            b = __builtin_bit_cast(
                                bf16x8, *(const uint4*)(w2b + (size_t)n * 256 + kk * 32 + quad * 8));
                        } else {
                            uint4 z; z.x = z.y = z.z = z.w = 0u;
                            b = __builtin_bit_cast(bf16x8, z);
                        }
                        a2[nt] = __builtin_amdgcn_mfma_f32_16x16x32_bf16(a, b, a2[nt], 0, 0, 0);
                    }
                }
#pragma unroll
                for (int nt = 0; nt < 2; ++nt) {
                    int n = nt * 16 + l16;
                    if (n < NCLS) {
                        float bv = b2[n];
#pragma unroll
                        for (int r = 0; r < 4; ++r)
                            lg[(quad * 4 + r) * 24 + n] = a2[nt][r] + bv;
                    }
                }
            }
            __syncthreads();
            if (tid < 16) {
                float v[NCLS];
                float mx = -3.4e38f;
#pragma unroll
                for (int c = 0; c < NCLS; ++c) { v[c] = lg[tid * 24 + c]; mx = fmaxf(mx, v[c]); }
                float s = 0.f;
#pragma unroll
                for (int c = 0; c < NCLS; ++c) s += __expf(v[c] - mx);
                float lse = mx + __logf(s);
                float* orow = out + ((size_t)(B0 + tid) * S_LEN + t) * NCLS;
#pragma unroll
                for (int c = 0; c < NCLS; ++c) orow[c] = v[c] - lse;
            }
            __syncthreads();
        }
    }
}

extern "C" void kernel_launch(void* const* d_in, const int* in_sizes, int n_in,
                              void* d_out, int out_size, void* d_ws, size_t ws_size,
                              hipStream_t stream) {
    const float* x    = (const float*)d_in[0];
    const float* w_ih = (const float*)d_in[1];
    const float* w_hh = (const float*)d_in[2];
    const float* b_ih = (const float*)d_in[3];
    const float* b_hh = (const float*)d_in[4];
    const float* w1   = (const float*)d_in[5];
    const float* b1   = (const float*)d_in[6];
    const float* w2   = (const float*)d_in[7];
    const float* b2   = (const float*)d_in[8];
    char* ws = (char*)d_ws;

    const size_t HS_BYTES = (size_t)16 * S_LEN * 16 * HID * 2;   // 128 MB
    const size_t NEED_BIG = HS_BYTES + 8192 + 262144 + 10240;

    if (ws_size >= NEED_BIG) {
        unsigned short* hsb   = (unsigned short*)ws;
        unsigned*       flags = (unsigned*)(ws + HS_BYTES);
        unsigned short* w1b   = (unsigned short*)(ws + HS_BYTES + 8192);
        unsigned short* w2b   = (unsigned short*)(ws + HS_BYTES + 8192 + 262144);
        prep_kernel<<<512, 256, 0, stream>>>(w1, w2, w1b, w2b, flags, 2048);
        lstm_big_kernel<<<256, 256, 0, stream>>>(x, w_ih, w_hh, b_ih, b_hh,
                                                 w1b, b1, w2b, b2,
                                                 (float*)d_out, hsb, flags);
    } else {
        unsigned short* hb    = (unsigned short*)ws;
        unsigned*       flags = (unsigned*)(ws + 4194304);
        unsigned*       done  = (unsigned*)(ws + 4194304 + 16384);
        unsigned short* w1b   = (unsigned short*)(ws + 4194304 + 16384 + 8192);
        unsigned short* w2b   = (unsigned short*)(ws + 4194304 + 16384 + 8192 + 262144);
        prep_kernel<<<512, 256, 0, stream>>>(w1, w2, w1b, w2b, flags, 6144);
        lstm_fused_kernel<<<384, 256, 0, stream>>>(x, w_ih, w_hh, b_ih, b_hh,
                                                   w1b, b1, w2b, b2,
                                                   (float*)d_out, hb, flags, done);
    }
}